// Round 16
// baseline (529.303 us; speedup 1.0000x reference)
//
#include <hip/hip_runtime.h>
#include <hip/hip_bf16.h>
#include <math.h>
#include <stdint.h>

#define NB 4
#define NN 2048
#define NA 128
#define NK 2048                         /* table intervals; knots 0..NK */
#define RMINF 5.8f
#define RMAXF 6.0f
#define PI_OVER_DR 15.707963267948966f  /* pi / (RMAX-RMIN) */

typedef __attribute__((ext_vector_type(8))) short short8v;   // 8 bf16 (MFMA A/B frag)
typedef __attribute__((ext_vector_type(4))) float f32x4;     // MFMA C/D frag

// Exact tanh via exp: tanh(x) = 1 - 2/(e^{2x}+1). ~7 VALU inst, rel err ~1e-6.
__device__ __forceinline__ float fast_tanh(float x)
{
    x = fminf(fmaxf(x, -15.f), 15.f);
    float e = __expf(2.f * x);
    float r = __builtin_amdgcn_rcpf(e + 1.f);
    return fmaf(-2.f, r, 1.f);
}

__device__ __forceinline__ uint16_t bf16_of(float x)
{
    __hip_bfloat16 b = __float2bfloat16(x);
    return *(uint16_t*)&b;
}

__device__ __forceinline__ float bf16_to_f(uint16_t v)
{
    union { uint32_t u; float f; } c; c.u = ((uint32_t)v) << 16; return c.f;
}

// Fragment-major packed element offset for an MFMA-A/B-side matrix X[R][Ktot]:
// tile (16 r x 32 k) = 512 contiguous elems; within tile, lane-major per the
// 16x16x32 frag map (lane = (r&15) + kg*16, elems k = kg*8..kg*8+7).
__device__ __forceinline__ size_t packed_off(int r, int k, int Ktot)
{
    return ((size_t)((r >> 4) * (Ktot >> 5) + (k >> 5)) << 9)
         + (((r & 15) + (((k >> 3) & 3) << 4)) << 3) + (k & 7);
}

// S value for table knot (shared by both table kernels).
__device__ __forceinline__ float knot_S(int knot)
{
    float uu = (float)knot / (float)NK;
    return (knot == NK) ? 1e8f : uu / (1.f - uu);
}

// ---------------------------------------------------------------------------
// Table stage A: H2[knot][j] = tanh(be1[j] + sum_k tanh(S*We0[k]+be0[k])*We1[k][j])
// ---------------------------------------------------------------------------
__global__ void prep_h2_kernel(
    const float* __restrict__ We0, const float* __restrict__ be0,
    const float* __restrict__ We1, const float* __restrict__ be1,
    float* __restrict__ H2)
{
    int idx = blockIdx.x * 256 + threadIdx.x;
    if (idx >= (NK + 1) * 50) return;
    int knot = idx / 50, j = idx - knot * 50;
    float S = knot_S(knot);
    float acc = be1[j];
    #pragma unroll
    for (int k = 0; k < 25; ++k) {
        float h1k = fast_tanh(fmaf(S, We0[k], be0[k]));
        acc = fmaf(h1k, We1[k * 50 + j], acc);
    }
    H2[idx] = fast_tanh(acc);
}

// ---------------------------------------------------------------------------
// Table stage B: TBL[knot][j] = tanh(be2[j] + sum_k H2[knot][k]*We2[k][j]).
// ---------------------------------------------------------------------------
__global__ void prep_tbl_kernel(
    const float* __restrict__ H2,
    const float* __restrict__ We2, const float* __restrict__ be2,
    float* __restrict__ TBL)
{
    int idx = blockIdx.x * 256 + threadIdx.x;
    if (idx >= (NK + 1) * 100) return;
    int knot = idx / 100, j = idx - knot * 100;
    const float* h2 = H2 + knot * 50;
    float acc = be2[j];
    #pragma unroll
    for (int k = 0; k < 50; ++k)
        acc = fmaf(h2[k], We2[k * 100 + j], acc);
    TBL[idx] = fast_tanh(acc);
}

// ---------------------------------------------------------------------------
// Prep: fitting weight W [K][240] fp32 -> Wt hi/lo PACKED [256][KP] bf16.
// ---------------------------------------------------------------------------
__global__ void prep_wt_kernel(const float* __restrict__ W,
                               uint16_t* __restrict__ Whi,
                               uint16_t* __restrict__ Wlo,
                               int K, int KP)
{
    int idx = blockIdx.x * 256 + threadIdx.x;
    if (idx < 256 * KP) {
        int colN = idx / KP, k = idx - colN * KP;
        float v = (colN < 240 && k < K) ? W[k * 240 + colN] : 0.f;
        uint16_t hi = bf16_of(v);
        size_t off = packed_off(colN, k, KP);
        Whi[off] = hi;
        Wlo[off] = bf16_of(v - bf16_to_f(hi));
    }
}

// ---------------------------------------------------------------------------
// Descriptor kernel v16: j-quad gather, depth-1 prefetch, VGPR <= 64 so
// __launch_bounds__(256,8) gives 8 waves/SIMD (R13-regime latency hiding
// with R14's instruction economy).
// ---------------------------------------------------------------------------
__global__ __launch_bounds__(256, 8) void desc_kernel(
    const float* __restrict__ dR, const int* __restrict__ neigh,
    const float* __restrict__ TBL,
    uint16_t* __restrict__ DRhi, uint16_t* __restrict__ DRlo)
{
    const int bid = blockIdx.x;
    const int atom = (bid & 7) * 1024 + (bid >> 3);   // bijection on [0,8192)
    const int t = threadIdx.x;

    __shared__ float4 RiSh[128];
    __shared__ float2 IFSh[128];            // (frac, as_float(ia*100))
    __shared__ float  tmpPart[8][4][100];   // 12.8 KB
    __shared__ float  tmpBf[4][100];
    __shared__ unsigned long long balls[2];

    // ---- phase A: one thread per neighbor (t<128) ----
    float x = 0.f, y = 0.f, z = 0.f, S = 0.f, s_inv = 1.f;
    if (t < 128) {
        const int base = atom * NA;
        x = dR[(base + t) * 3 + 0];
        y = dR[(base + t) * 3 + 1];
        z = dR[(base + t) * 3 + 2];
        int nb = neigh[base + t];
        float Rij = x * x + y * y + z * z;      // squared distance (ref quirk)
        bool mask = nb > 0;
        bool mask_min = Rij < RMINF;
        float safe = (Rij > 0.f) ? Rij : 1.f;
        s_inv = 1.f / safe;
        float s_cos = 0.5f * cosf((Rij - RMINF) * PI_OVER_DR) + 0.5f;
        S = (mask && mask_min) ? s_inv
          : ((!mask_min && Rij < RMAXF) ? s_cos : 0.f);
        unsigned long long bal = __ballot(mask);
        if ((t & 63) == 0) balls[t >> 6] = bal;
    }
    __syncthreads();   // #1: balls visible

    if (t < 128) {
        unsigned long long nb0 = ~balls[0], nb1 = ~balls[1];
        int firstBad;
        if (nb0)       firstBad = __ffsll((long long)nb0) - 1;
        else if (nb1)  firstBad = 64 + __ffsll((long long)nb1) - 1;
        else           firstBad = 128;
        float f = (t < firstBad) ? (S * s_inv) : 0.f;
        RiSh[t] = make_float4(S, f * x, f * y, f * z);
        float uu = S / (1.f + S);               // match prep map exactly
        float pos = fminf(uu * (float)NK, (float)NK - 0.001f);
        float fi = floorf(pos);
        IFSh[t] = make_float2(pos - fi, __int_as_float((int)fi * 100));
    }
    __syncthreads();   // #2: RiSh + IFSh ready

    // ---- phase B: j-quad gather-contraction, depth-1 prefetch ----
    const int aq = t >> 5;          // 0..7 -> a-chunk of 16
    const int jq = t & 31;          // j-quad index, active < 25
    if (jq < 25) {
        const float* TBLq = TBL + jq * 4;
        const int a0 = aq * 16;

        float acc00 = 0.f, acc01 = 0.f, acc02 = 0.f, acc03 = 0.f;
        float acc10 = 0.f, acc11 = 0.f, acc12 = 0.f, acc13 = 0.f;
        float acc20 = 0.f, acc21 = 0.f, acc22 = 0.f, acc23 = 0.f;
        float acc30 = 0.f, acc31 = 0.f, acc32 = 0.f, acc33 = 0.f;

        // depth-1 prefetch of (ifv, ri, table rows)
        float2 ifv = IFSh[a0];
        float4 ri  = RiSh[a0];
        float4 t0, t1;
        {
            int ia = __float_as_int(ifv.y);
            t0 = *(const float4*)(TBLq + ia);
            t1 = *(const float4*)(TBLq + ia + 100);
        }
        #pragma unroll
        for (int i = 0; i < 16; ++i) {
            float  cf = ifv.x;
            float4 c0 = t0, c1 = t1, cri = ri;
            if (i + 1 < 16) {
                ifv = IFSh[a0 + i + 1];
                ri  = RiSh[a0 + i + 1];
                int ia = __float_as_int(ifv.y);
                t0 = *(const float4*)(TBLq + ia);
                t1 = *(const float4*)(TBLq + ia + 100);
            }
            float g0 = fmaf(cf, c1.x - c0.x, c0.x);
            float g1 = fmaf(cf, c1.y - c0.y, c0.y);
            float g2 = fmaf(cf, c1.z - c0.z, c0.z);
            float g3 = fmaf(cf, c1.w - c0.w, c0.w);
            acc00 = fmaf(cri.x, g0, acc00); acc01 = fmaf(cri.x, g1, acc01);
            acc02 = fmaf(cri.x, g2, acc02); acc03 = fmaf(cri.x, g3, acc03);
            acc10 = fmaf(cri.y, g0, acc10); acc11 = fmaf(cri.y, g1, acc11);
            acc12 = fmaf(cri.y, g2, acc12); acc13 = fmaf(cri.y, g3, acc13);
            acc20 = fmaf(cri.z, g0, acc20); acc21 = fmaf(cri.z, g1, acc21);
            acc22 = fmaf(cri.z, g2, acc22); acc23 = fmaf(cri.z, g3, acc23);
            acc30 = fmaf(cri.w, g0, acc30); acc31 = fmaf(cri.w, g1, acc31);
            acc32 = fmaf(cri.w, g2, acc32); acc33 = fmaf(cri.w, g3, acc33);
        }
        *(float4*)&tmpPart[aq][0][jq * 4] = make_float4(acc00, acc01, acc02, acc03);
        *(float4*)&tmpPart[aq][1][jq * 4] = make_float4(acc10, acc11, acc12, acc13);
        *(float4*)&tmpPart[aq][2][jq * 4] = make_float4(acc20, acc21, acc22, acc23);
        *(float4*)&tmpPart[aq][3][jq * 4] = make_float4(acc30, acc31, acc32, acc33);
    }
    __syncthreads();   // #3

    // ---- reduce 8 a-chunks ----
    for (int idx = t; idx < 400; idx += 256) {
        int c = idx / 100, j = idx - c * 100;
        float s = tmpPart[0][c][j] + tmpPart[1][c][j]
                + tmpPart[2][c][j] + tmpPart[3][c][j]
                + tmpPart[4][c][j] + tmpPart[5][c][j]
                + tmpPart[6][c][j] + tmpPart[7][c][j];
        tmpBf[c][j] = s;
    }
    __syncthreads();   // #4

    // ---- phase C: DR[i][M] -> bf16 hi/lo PACKED; i split by half ----
    const int half = t >> 7;
    const int u = t & 127;
    if (u < 100) {
        float b0 = tmpBf[0][u];
        float b1 = tmpBf[1][u];
        float b2 = tmpBf[2][u];
        float b3 = tmpBf[3][u];
        const int i0 = half * 8;
        #pragma unroll
        for (int ii = 0; ii < 8; ++ii) {
            int i = i0 + ii;
            float v = tmpBf[0][i] * b0 + tmpBf[1][i] * b1
                    + tmpBf[2][i] * b2 + tmpBf[3][i] * b3;
            uint16_t hi = bf16_of(v);
            size_t off = packed_off(atom, i * 100 + u, 1600);
            DRhi[off] = hi;
            DRlo[off] = bf16_of(v - bf16_to_f(hi));
        }
    }
}

// ---------------------------------------------------------------------------
// GEMM partials from PACKED operands: Part[z][8192][256] (fp32, row-major).
// 256 thr = 4 waves (2mg x 2ng), per-wave 32x32, BM=BN=64.
// Grid (128, 4, KSPLIT) = 1024 blocks. Register double-buffer, fully unrolled.
// ---------------------------------------------------------------------------
template<int KP, int KSPLIT>
__global__ __launch_bounds__(256, 4) void gemm_part(
    const uint16_t* __restrict__ Ahi, const uint16_t* __restrict__ Alo,
    const uint16_t* __restrict__ Wthi, const uint16_t* __restrict__ Wtlo,
    float* __restrict__ Part)
{
    constexpr int KT = KP >> 5;              // total k-tiles
    constexpr int STEPS = KT / KSPLIT;       // k-tiles this chunk
    const int tid = threadIdx.x;
    const int wid = tid >> 6, lane = tid & 63;
    const int mg = wid >> 1, ng = wid & 1;
    const int mt0 = blockIdx.x * 4 + mg * 2;
    const int nt0 = blockIdx.y * 4 + ng * 2;
    const int kt0 = blockIdx.z * STEPS;

    const size_t aB0 = ((size_t)(mt0 + 0) * KT + kt0) * 512 + lane * 8;
    const size_t aB1 = ((size_t)(mt0 + 1) * KT + kt0) * 512 + lane * 8;
    const size_t bB0 = ((size_t)(nt0 + 0) * KT + kt0) * 512 + lane * 8;
    const size_t bB1 = ((size_t)(nt0 + 1) * KT + kt0) * 512 + lane * 8;

    f32x4 acc[2][2];
    #pragma unroll
    for (int m = 0; m < 2; ++m)
        #pragma unroll
        for (int n = 0; n < 2; ++n) acc[m][n] = (f32x4){0.f, 0.f, 0.f, 0.f};

    short8v f[2][8];

#define LOADSET(B, S) do {                                       \
        f[B][0] = *(const short8v*)(Ahi  + aB0 + (S) * 512);     \
        f[B][1] = *(const short8v*)(Ahi  + aB1 + (S) * 512);     \
        f[B][2] = *(const short8v*)(Alo  + aB0 + (S) * 512);     \
        f[B][3] = *(const short8v*)(Alo  + aB1 + (S) * 512);     \
        f[B][4] = *(const short8v*)(Wthi + bB0 + (S) * 512);     \
        f[B][5] = *(const short8v*)(Wthi + bB1 + (S) * 512);     \
        f[B][6] = *(const short8v*)(Wtlo + bB0 + (S) * 512);     \
        f[B][7] = *(const short8v*)(Wtlo + bB1 + (S) * 512);     \
    } while (0)

    LOADSET(0, 0);
    #pragma unroll
    for (int s = 0; s < STEPS; ++s) {
        const int b = s & 1;
        if (s + 1 < STEPS) LOADSET(b ^ 1, s + 1);
        #pragma unroll
        for (int m = 0; m < 2; ++m)
            #pragma unroll
            for (int n = 0; n < 2; ++n) {
                acc[m][n] = __builtin_amdgcn_mfma_f32_16x16x32_bf16(f[b][m],     f[b][4 + n], acc[m][n], 0, 0, 0);
                acc[m][n] = __builtin_amdgcn_mfma_f32_16x16x32_bf16(f[b][m],     f[b][6 + n], acc[m][n], 0, 0, 0);
                acc[m][n] = __builtin_amdgcn_mfma_f32_16x16x32_bf16(f[b][2 + m], f[b][4 + n], acc[m][n], 0, 0, 0);
            }
    }
#undef LOADSET

    const int ar = lane & 15, kg = lane >> 4;
    float* pp = Part + (size_t)blockIdx.z * (8192 * 256);
    #pragma unroll
    for (int m = 0; m < 2; ++m)
        #pragma unroll
        for (int n = 0; n < 2; ++n)
            #pragma unroll
            for (int r = 0; r < 4; ++r)
                pp[(size_t)((mt0 + m) * 16 + kg * 4 + r) * 256 + (nt0 + n) * 16 + ar] = acc[m][n][r];
}

// ---------------------------------------------------------------------------
// Epilogue: O = tanh(sum_z Part[z] + bias) -> bf16 hi/lo PACKED (Ktot=256).
// XCD-swizzled so the 4 blocks covering each 16-row packed tile share an L2.
// ---------------------------------------------------------------------------
__global__ __launch_bounds__(256) void gemm_epi(
    const float* __restrict__ Part, const float* __restrict__ bias,
    uint16_t* __restrict__ Ohi, uint16_t* __restrict__ Olo)
{
    int g = (blockIdx.x & 7) * 256 + (blockIdx.x >> 3);   // bijection on [0,2048)
    int idx0 = g * 1024 + threadIdx.x;
    #pragma unroll
    for (int it = 0; it < 4; ++it) {
        int idx = idx0 + it * 256;
        int col = idx & 255;
        int row = idx >> 8;
        float s = Part[idx] + Part[idx + 8192 * 256];
        float v = (col < 240) ? fast_tanh(s + bias[col]) : 0.f;
        uint16_t hi = bf16_of(v);
        size_t off = packed_off(row, col, 256);
        Ohi[off] = hi;
        Olo[off] = bf16_of(v - bf16_to_f(hi));
    }
}

// ---------------------------------------------------------------------------
// Ei = (h_hi+h_lo) @ Wf3 + bf3 : one wave per atom; H is PACKED (Ktot=256).
// ---------------------------------------------------------------------------
__global__ __launch_bounds__(256) void final_dot_kernel(
    const uint16_t* __restrict__ Hhi, const uint16_t* __restrict__ Hlo,
    const float* __restrict__ Wf3, const float* __restrict__ bf3,
    float* __restrict__ out)
{
    int wave = threadIdx.x >> 6, lane = threadIdx.x & 63;
    int atom = blockIdx.x * 4 + wave;
    float v = 0.f;
    if (lane < 60) {
        size_t off = packed_off(atom, lane * 4, 256);
        ushort4 h4 = *(const ushort4*)(Hhi + off);
        ushort4 l4 = *(const ushort4*)(Hlo + off);
        float4 w = *(const float4*)&Wf3[lane * 4];
        v = (bf16_to_f(h4.x) + bf16_to_f(l4.x)) * w.x
          + (bf16_to_f(h4.y) + bf16_to_f(l4.y)) * w.y
          + (bf16_to_f(h4.z) + bf16_to_f(l4.z)) * w.z
          + (bf16_to_f(h4.w) + bf16_to_f(l4.w)) * w.w;
    }
    #pragma unroll
    for (int off = 32; off; off >>= 1) v += __shfl_down(v, off, 64);
    if (lane == 0) out[4 + atom] = v + bf3[0];
}

__global__ __launch_bounds__(256) void etot_kernel(float* __restrict__ out)
{
    __shared__ float red[256];
    int b = blockIdx.x, t = threadIdx.x;
    float s = 0.f;
    for (int i = t; i < NN; i += 256) s += out[4 + b * NN + i];
    red[t] = s;
    __syncthreads();
    for (int w = 128; w; w >>= 1) {
        if (t < w) red[t] += red[t + w];
        __syncthreads();
    }
    if (t == 0) out[b] = red[0];
}

// ---------------------------------------------------------------------------
extern "C" void kernel_launch(void* const* d_in, const int* in_sizes, int n_in,
                              void* d_out, int out_size, void* d_ws, size_t ws_size,
                              hipStream_t stream)
{
    const float* dR    = (const float*)d_in[0];
    const int*   neigh = (const int*)d_in[1];
    const float* We0   = (const float*)d_in[2];
    const float* be0   = (const float*)d_in[3];
    const float* We1   = (const float*)d_in[4];
    const float* be1   = (const float*)d_in[5];
    const float* We2   = (const float*)d_in[6];
    const float* be2   = (const float*)d_in[7];
    const float* Wf0   = (const float*)d_in[8];
    const float* bf0   = (const float*)d_in[9];
    const float* Wf1   = (const float*)d_in[10];
    const float* bf1   = (const float*)d_in[11];
    const float* Wf2   = (const float*)d_in[12];
    const float* bf2   = (const float*)d_in[13];
    const float* Wf3   = (const float*)d_in[14];
    const float* bf3   = (const float*)d_in[15];
    float* out = (float*)d_out;

    char* ws = (char*)d_ws;
    uint16_t* Wt0hi  = (uint16_t*)(ws + 32768);               // 819200
    uint16_t* Wt0lo  = (uint16_t*)(ws + 851968);              // 819200
    uint16_t* Wt1hi  = (uint16_t*)(ws + 1671168);             // 131072
    uint16_t* Wt1lo  = (uint16_t*)(ws + 1802240);             // 131072
    uint16_t* Wt2hi  = (uint16_t*)(ws + 1933312);             // 131072
    uint16_t* Wt2lo  = (uint16_t*)(ws + 2064384);             // 131072
    uint16_t* DRhi   = (uint16_t*)(ws + 2195456);             // 26214400
    uint16_t* DRlo   = (uint16_t*)(ws + 28409856);            // 26214400
    uint16_t* hAhi   = (uint16_t*)(ws + 54624256);            // 4194304
    uint16_t* hAlo   = (uint16_t*)(ws + 58818560);            // 4194304
    uint16_t* hBhi   = (uint16_t*)(ws + 63012864);            // 4194304
    uint16_t* hBlo   = (uint16_t*)(ws + 67207168);            // 4194304
    // H2 (410KB) aliases hAhi: written by prep_h2, read by prep_tbl,
    // dead before epi1 writes hA.
    float* H2  = (float*)(ws + 54624256);
    // TBL (820KB) aliases hBhi: read by desc before gemm1 overwrites w/ Part1.
    float* TBL = (float*)(ws + 63012864);
    // Part1 (2x8.4MB fp32) aliases [hBhi..]: written by gemm1 (TBL dead),
    // read by epi1 (writes hA, disjoint), dead before epi2 writes hB.
    float* Part1 = (float*)(ws + 63012864);
    // Part2 aliases the DR region (dead after gemm1 reads it).
    float* Part2 = (float*)(ws + 2195456);

    prep_h2_kernel<<<401, 256, 0, stream>>>(We0, be0, We1, be1, H2);
    prep_tbl_kernel<<<801, 256, 0, stream>>>(H2, We2, be2, TBL);
    prep_wt_kernel<<<1600, 256, 0, stream>>>(Wf0, Wt0hi, Wt0lo, 1600, 1600);
    prep_wt_kernel<<<256, 256, 0, stream>>>(Wf1, Wt1hi, Wt1lo, 240, 256);
    prep_wt_kernel<<<256, 256, 0, stream>>>(Wf2, Wt2hi, Wt2lo, 240, 256);

    desc_kernel<<<NB * NN, 256, 0, stream>>>(dR, neigh, TBL, DRhi, DRlo);

    gemm_part<1600, 2><<<dim3(128, 4, 2), 256, 0, stream>>>(DRhi, DRlo, Wt0hi, Wt0lo, Part1);
    gemm_epi<<<2048, 256, 0, stream>>>(Part1, bf0, hAhi, hAlo);
    gemm_part<256, 2><<<dim3(128, 4, 2), 256, 0, stream>>>(hAhi, hAlo, Wt1hi, Wt1lo, Part2);
    gemm_epi<<<2048, 256, 0, stream>>>(Part2, bf1, hBhi, hBlo);
    gemm_part<256, 2><<<dim3(128, 4, 2), 256, 0, stream>>>(hBhi, hBlo, Wt2hi, Wt2lo, Part2);
    gemm_epi<<<2048, 256, 0, stream>>>(Part2, bf2, hAhi, hAlo);

    final_dot_kernel<<<NB * NN / 4, 256, 0, stream>>>(hAhi, hAlo, Wf3, bf3, out);
    etot_kernel<<<NB, 256, 0, stream>>>(out);
}

// Round 17
// 174.096 us; speedup vs baseline: 3.0403x; 3.0403x over previous
//
#include <hip/hip_runtime.h>
#include <hip/hip_bf16.h>
#include <math.h>
#include <stdint.h>

#define NB 4
#define NN 2048
#define NA 128
#define NK 2048                         /* table intervals; knots 0..NK */
#define RMINF 5.8f
#define RMAXF 6.0f
#define PI_OVER_DR 15.707963267948966f  /* pi / (RMAX-RMIN) */

typedef __attribute__((ext_vector_type(8))) short short8v;   // 8 bf16 (MFMA A/B frag)
typedef __attribute__((ext_vector_type(4))) float f32x4;     // MFMA C/D frag

// Exact tanh via exp: tanh(x) = 1 - 2/(e^{2x}+1). ~7 VALU inst, rel err ~1e-6.
__device__ __forceinline__ float fast_tanh(float x)
{
    x = fminf(fmaxf(x, -15.f), 15.f);
    float e = __expf(2.f * x);
    float r = __builtin_amdgcn_rcpf(e + 1.f);
    return fmaf(-2.f, r, 1.f);
}

__device__ __forceinline__ uint16_t bf16_of(float x)
{
    __hip_bfloat16 b = __float2bfloat16(x);
    return *(uint16_t*)&b;
}

__device__ __forceinline__ float bf16_to_f(uint16_t v)
{
    union { uint32_t u; float f; } c; c.u = ((uint32_t)v) << 16; return c.f;
}

// Fragment-major packed element offset for an MFMA-A/B-side matrix X[R][Ktot]:
// tile (16 r x 32 k) = 512 contiguous elems; within tile, lane-major per the
// 16x16x32 frag map (lane = (r&15) + kg*16, elems k = kg*8..kg*8+7).
__device__ __forceinline__ size_t packed_off(int r, int k, int Ktot)
{
    return ((size_t)((r >> 4) * (Ktot >> 5) + (k >> 5)) << 9)
         + (((r & 15) + (((k >> 3) & 3) << 4)) << 3) + (k & 7);
}

// S value for table knot (shared by both table kernels).
__device__ __forceinline__ float knot_S(int knot)
{
    float uu = (float)knot / (float)NK;
    return (knot == NK) ? 1e8f : uu / (1.f - uu);
}

// ---------------------------------------------------------------------------
// Table stage A: H2[knot][j] = tanh(be1[j] + sum_k tanh(S*We0[k]+be0[k])*We1[k][j])
// ---------------------------------------------------------------------------
__global__ void prep_h2_kernel(
    const float* __restrict__ We0, const float* __restrict__ be0,
    const float* __restrict__ We1, const float* __restrict__ be1,
    float* __restrict__ H2)
{
    int idx = blockIdx.x * 256 + threadIdx.x;
    if (idx >= (NK + 1) * 50) return;
    int knot = idx / 50, j = idx - knot * 50;
    float S = knot_S(knot);
    float acc = be1[j];
    #pragma unroll
    for (int k = 0; k < 25; ++k) {
        float h1k = fast_tanh(fmaf(S, We0[k], be0[k]));
        acc = fmaf(h1k, We1[k * 50 + j], acc);
    }
    H2[idx] = fast_tanh(acc);
}

// ---------------------------------------------------------------------------
// Table stage B: TBL[knot][j] = tanh(be2[j] + sum_k H2[knot][k]*We2[k][j]).
// ---------------------------------------------------------------------------
__global__ void prep_tbl_kernel(
    const float* __restrict__ H2,
    const float* __restrict__ We2, const float* __restrict__ be2,
    float* __restrict__ TBL)
{
    int idx = blockIdx.x * 256 + threadIdx.x;
    if (idx >= (NK + 1) * 100) return;
    int knot = idx / 100, j = idx - knot * 100;
    const float* h2 = H2 + knot * 50;
    float acc = be2[j];
    #pragma unroll
    for (int k = 0; k < 50; ++k)
        acc = fmaf(h2[k], We2[k * 100 + j], acc);
    TBL[idx] = fast_tanh(acc);
}

// ---------------------------------------------------------------------------
// Prep: fitting weight W [K][240] fp32 -> Wt hi/lo PACKED [256][KP] bf16.
// ---------------------------------------------------------------------------
__global__ void prep_wt_kernel(const float* __restrict__ W,
                               uint16_t* __restrict__ Whi,
                               uint16_t* __restrict__ Wlo,
                               int K, int KP)
{
    int idx = blockIdx.x * 256 + threadIdx.x;
    if (idx < 256 * KP) {
        int colN = idx / KP, k = idx - colN * KP;
        float v = (colN < 240 && k < K) ? W[k * 240 + colN] : 0.f;
        uint16_t hi = bf16_of(v);
        size_t off = packed_off(colN, k, KP);
        Whi[off] = hi;
        Wlo[off] = bf16_of(v - bf16_to_f(hi));
    }
}

// ---------------------------------------------------------------------------
// Descriptor kernel v17: j-PAIR gather (8 acc regs -> small live set, aim
// for natural VGPR <= 64 = 8 waves/SIMD; NO forced launch bound).
//  phase A (t<128): S, ballot, Ri, (frac, ia*100 as int bits)
//  phase B: thread (aq = t>>6 in [0,4) chunk of 32 a, jp = t&63 < 50):
//           32 a-iters, float2 table loads, depth-1 prefetch, 2 lerps + 8 FMA.
//  reduce 4 partials -> tmpBf; phase C: DR bf16 hi/lo PACKED (atom-swizzled).
// ---------------------------------------------------------------------------
__global__ __launch_bounds__(256) void desc_kernel(
    const float* __restrict__ dR, const int* __restrict__ neigh,
    const float* __restrict__ TBL,
    uint16_t* __restrict__ DRhi, uint16_t* __restrict__ DRlo)
{
    const int bid = blockIdx.x;
    const int atom = (bid & 7) * 1024 + (bid >> 3);   // bijection on [0,8192)
    const int t = threadIdx.x;

    __shared__ float4 RiSh[128];
    __shared__ float2 IFSh[128];            // (frac, as_float(ia*100))
    __shared__ float  tmpPart[4][4][100];   // 6.4 KB
    __shared__ float  tmpBf[4][100];
    __shared__ unsigned long long balls[2];

    // ---- phase A: one thread per neighbor (t<128) ----
    float x = 0.f, y = 0.f, z = 0.f, S = 0.f, s_inv = 1.f;
    if (t < 128) {
        const int base = atom * NA;
        x = dR[(base + t) * 3 + 0];
        y = dR[(base + t) * 3 + 1];
        z = dR[(base + t) * 3 + 2];
        int nb = neigh[base + t];
        float Rij = x * x + y * y + z * z;      // squared distance (ref quirk)
        bool mask = nb > 0;
        bool mask_min = Rij < RMINF;
        float safe = (Rij > 0.f) ? Rij : 1.f;
        s_inv = 1.f / safe;
        float s_cos = 0.5f * cosf((Rij - RMINF) * PI_OVER_DR) + 0.5f;
        S = (mask && mask_min) ? s_inv
          : ((!mask_min && Rij < RMAXF) ? s_cos : 0.f);
        unsigned long long bal = __ballot(mask);
        if ((t & 63) == 0) balls[t >> 6] = bal;
    }
    __syncthreads();   // #1: balls visible

    if (t < 128) {
        unsigned long long nb0 = ~balls[0], nb1 = ~balls[1];
        int firstBad;
        if (nb0)       firstBad = __ffsll((long long)nb0) - 1;
        else if (nb1)  firstBad = 64 + __ffsll((long long)nb1) - 1;
        else           firstBad = 128;
        float f = (t < firstBad) ? (S * s_inv) : 0.f;
        RiSh[t] = make_float4(S, f * x, f * y, f * z);
        float uu = S / (1.f + S);               // match prep map exactly
        float pos = fminf(uu * (float)NK, (float)NK - 0.001f);
        float fi = floorf(pos);
        IFSh[t] = make_float2(pos - fi, __int_as_float((int)fi * 100));
    }
    __syncthreads();   // #2: RiSh + IFSh ready

    // ---- phase B: j-pair gather-contraction, depth-1 prefetch ----
    const int aq = t >> 6;          // 0..3 -> a-chunk of 32
    const int jp = t & 63;          // j-pair index, active < 50
    if (jp < 50) {
        const float* TBLp = TBL + jp * 2;
        const int a0 = aq * 32;

        float acc00 = 0.f, acc01 = 0.f;
        float acc10 = 0.f, acc11 = 0.f;
        float acc20 = 0.f, acc21 = 0.f;
        float acc30 = 0.f, acc31 = 0.f;

        // depth-1 prefetch of (ifv, table pair rows)
        float2 ifv = IFSh[a0];
        float2 t0, t1;
        {
            int ia = __float_as_int(ifv.y);
            t0 = *(const float2*)(TBLp + ia);
            t1 = *(const float2*)(TBLp + ia + 100);
        }
        #pragma unroll 4
        for (int i = 0; i < 32; ++i) {
            float  cf = ifv.x;
            float2 c0 = t0, c1 = t1;
            float4 cri = RiSh[a0 + i];
            if (i + 1 < 32) {
                ifv = IFSh[a0 + i + 1];
                int ia = __float_as_int(ifv.y);
                t0 = *(const float2*)(TBLp + ia);
                t1 = *(const float2*)(TBLp + ia + 100);
            }
            float g0 = fmaf(cf, c1.x - c0.x, c0.x);
            float g1 = fmaf(cf, c1.y - c0.y, c0.y);
            acc00 = fmaf(cri.x, g0, acc00); acc01 = fmaf(cri.x, g1, acc01);
            acc10 = fmaf(cri.y, g0, acc10); acc11 = fmaf(cri.y, g1, acc11);
            acc20 = fmaf(cri.z, g0, acc20); acc21 = fmaf(cri.z, g1, acc21);
            acc30 = fmaf(cri.w, g0, acc30); acc31 = fmaf(cri.w, g1, acc31);
        }
        *(float2*)&tmpPart[aq][0][jp * 2] = make_float2(acc00, acc01);
        *(float2*)&tmpPart[aq][1][jp * 2] = make_float2(acc10, acc11);
        *(float2*)&tmpPart[aq][2][jp * 2] = make_float2(acc20, acc21);
        *(float2*)&tmpPart[aq][3][jp * 2] = make_float2(acc30, acc31);
    }
    __syncthreads();   // #3

    // ---- reduce 4 a-chunks ----
    for (int idx = t; idx < 400; idx += 256) {
        int c = idx / 100, j = idx - c * 100;
        tmpBf[c][j] = tmpPart[0][c][j] + tmpPart[1][c][j]
                    + tmpPart[2][c][j] + tmpPart[3][c][j];
    }
    __syncthreads();   // #4

    // ---- phase C: DR[i][M] -> bf16 hi/lo PACKED; i split by half ----
    const int half = t >> 7;
    const int u = t & 127;
    if (u < 100) {
        float b0 = tmpBf[0][u];
        float b1 = tmpBf[1][u];
        float b2 = tmpBf[2][u];
        float b3 = tmpBf[3][u];
        const int i0 = half * 8;
        #pragma unroll
        for (int ii = 0; ii < 8; ++ii) {
            int i = i0 + ii;
            float v = tmpBf[0][i] * b0 + tmpBf[1][i] * b1
                    + tmpBf[2][i] * b2 + tmpBf[3][i] * b3;
            uint16_t hi = bf16_of(v);
            size_t off = packed_off(atom, i * 100 + u, 1600);
            DRhi[off] = hi;
            DRlo[off] = bf16_of(v - bf16_to_f(hi));
        }
    }
}

// ---------------------------------------------------------------------------
// GEMM partials from PACKED operands: Part[z][8192][256] (fp32, row-major).
// 256 thr = 4 waves (2mg x 2ng), per-wave 32x32, BM=BN=64.
// Grid (128, 4, KSPLIT) = 1024 blocks. Register double-buffer, fully unrolled.
// ---------------------------------------------------------------------------
template<int KP, int KSPLIT>
__global__ __launch_bounds__(256, 4) void gemm_part(
    const uint16_t* __restrict__ Ahi, const uint16_t* __restrict__ Alo,
    const uint16_t* __restrict__ Wthi, const uint16_t* __restrict__ Wtlo,
    float* __restrict__ Part)
{
    constexpr int KT = KP >> 5;              // total k-tiles
    constexpr int STEPS = KT / KSPLIT;       // k-tiles this chunk
    const int tid = threadIdx.x;
    const int wid = tid >> 6, lane = tid & 63;
    const int mg = wid >> 1, ng = wid & 1;
    const int mt0 = blockIdx.x * 4 + mg * 2;
    const int nt0 = blockIdx.y * 4 + ng * 2;
    const int kt0 = blockIdx.z * STEPS;

    const size_t aB0 = ((size_t)(mt0 + 0) * KT + kt0) * 512 + lane * 8;
    const size_t aB1 = ((size_t)(mt0 + 1) * KT + kt0) * 512 + lane * 8;
    const size_t bB0 = ((size_t)(nt0 + 0) * KT + kt0) * 512 + lane * 8;
    const size_t bB1 = ((size_t)(nt0 + 1) * KT + kt0) * 512 + lane * 8;

    f32x4 acc[2][2];
    #pragma unroll
    for (int m = 0; m < 2; ++m)
        #pragma unroll
        for (int n = 0; n < 2; ++n) acc[m][n] = (f32x4){0.f, 0.f, 0.f, 0.f};

    short8v f[2][8];

#define LOADSET(B, S) do {                                       \
        f[B][0] = *(const short8v*)(Ahi  + aB0 + (S) * 512);     \
        f[B][1] = *(const short8v*)(Ahi  + aB1 + (S) * 512);     \
        f[B][2] = *(const short8v*)(Alo  + aB0 + (S) * 512);     \
        f[B][3] = *(const short8v*)(Alo  + aB1 + (S) * 512);     \
        f[B][4] = *(const short8v*)(Wthi + bB0 + (S) * 512);     \
        f[B][5] = *(const short8v*)(Wthi + bB1 + (S) * 512);     \
        f[B][6] = *(const short8v*)(Wtlo + bB0 + (S) * 512);     \
        f[B][7] = *(const short8v*)(Wtlo + bB1 + (S) * 512);     \
    } while (0)

    LOADSET(0, 0);
    #pragma unroll
    for (int s = 0; s < STEPS; ++s) {
        const int b = s & 1;
        if (s + 1 < STEPS) LOADSET(b ^ 1, s + 1);
        #pragma unroll
        for (int m = 0; m < 2; ++m)
            #pragma unroll
            for (int n = 0; n < 2; ++n) {
                acc[m][n] = __builtin_amdgcn_mfma_f32_16x16x32_bf16(f[b][m],     f[b][4 + n], acc[m][n], 0, 0, 0);
                acc[m][n] = __builtin_amdgcn_mfma_f32_16x16x32_bf16(f[b][m],     f[b][6 + n], acc[m][n], 0, 0, 0);
                acc[m][n] = __builtin_amdgcn_mfma_f32_16x16x32_bf16(f[b][2 + m], f[b][4 + n], acc[m][n], 0, 0, 0);
            }
    }
#undef LOADSET

    const int ar = lane & 15, kg = lane >> 4;
    float* pp = Part + (size_t)blockIdx.z * (8192 * 256);
    #pragma unroll
    for (int m = 0; m < 2; ++m)
        #pragma unroll
        for (int n = 0; n < 2; ++n)
            #pragma unroll
            for (int r = 0; r < 4; ++r)
                pp[(size_t)((mt0 + m) * 16 + kg * 4 + r) * 256 + (nt0 + n) * 16 + ar] = acc[m][n][r];
}

// ---------------------------------------------------------------------------
// Epilogue: O = tanh(sum_z Part[z] + bias) -> bf16 hi/lo PACKED (Ktot=256).
// XCD-swizzled so the 4 blocks covering each 16-row packed tile share an L2.
// ---------------------------------------------------------------------------
__global__ __launch_bounds__(256) void gemm_epi(
    const float* __restrict__ Part, const float* __restrict__ bias,
    uint16_t* __restrict__ Ohi, uint16_t* __restrict__ Olo)
{
    int g = (blockIdx.x & 7) * 256 + (blockIdx.x >> 3);   // bijection on [0,2048)
    int idx0 = g * 1024 + threadIdx.x;
    #pragma unroll
    for (int it = 0; it < 4; ++it) {
        int idx = idx0 + it * 256;
        int col = idx & 255;
        int row = idx >> 8;
        float s = Part[idx] + Part[idx + 8192 * 256];
        float v = (col < 240) ? fast_tanh(s + bias[col]) : 0.f;
        uint16_t hi = bf16_of(v);
        size_t off = packed_off(row, col, 256);
        Ohi[off] = hi;
        Olo[off] = bf16_of(v - bf16_to_f(hi));
    }
}

// ---------------------------------------------------------------------------
// Ei = (h_hi+h_lo) @ Wf3 + bf3 : one wave per atom; H is PACKED (Ktot=256).
// ---------------------------------------------------------------------------
__global__ __launch_bounds__(256) void final_dot_kernel(
    const uint16_t* __restrict__ Hhi, const uint16_t* __restrict__ Hlo,
    const float* __restrict__ Wf3, const float* __restrict__ bf3,
    float* __restrict__ out)
{
    int wave = threadIdx.x >> 6, lane = threadIdx.x & 63;
    int atom = blockIdx.x * 4 + wave;
    float v = 0.f;
    if (lane < 60) {
        size_t off = packed_off(atom, lane * 4, 256);
        ushort4 h4 = *(const ushort4*)(Hhi + off);
        ushort4 l4 = *(const ushort4*)(Hlo + off);
        float4 w = *(const float4*)&Wf3[lane * 4];
        v = (bf16_to_f(h4.x) + bf16_to_f(l4.x)) * w.x
          + (bf16_to_f(h4.y) + bf16_to_f(l4.y)) * w.y
          + (bf16_to_f(h4.z) + bf16_to_f(l4.z)) * w.z
          + (bf16_to_f(h4.w) + bf16_to_f(l4.w)) * w.w;
    }
    #pragma unroll
    for (int off = 32; off; off >>= 1) v += __shfl_down(v, off, 64);
    if (lane == 0) out[4 + atom] = v + bf3[0];
}

__global__ __launch_bounds__(256) void etot_kernel(float* __restrict__ out)
{
    __shared__ float red[256];
    int b = blockIdx.x, t = threadIdx.x;
    float s = 0.f;
    for (int i = t; i < NN; i += 256) s += out[4 + b * NN + i];
    red[t] = s;
    __syncthreads();
    for (int w = 128; w; w >>= 1) {
        if (t < w) red[t] += red[t + w];
        __syncthreads();
    }
    if (t == 0) out[b] = red[0];
}

// ---------------------------------------------------------------------------
extern "C" void kernel_launch(void* const* d_in, const int* in_sizes, int n_in,
                              void* d_out, int out_size, void* d_ws, size_t ws_size,
                              hipStream_t stream)
{
    const float* dR    = (const float*)d_in[0];
    const int*   neigh = (const int*)d_in[1];
    const float* We0   = (const float*)d_in[2];
    const float* be0   = (const float*)d_in[3];
    const float* We1   = (const float*)d_in[4];
    const float* be1   = (const float*)d_in[5];
    const float* We2   = (const float*)d_in[6];
    const float* be2   = (const float*)d_in[7];
    const float* Wf0   = (const float*)d_in[8];
    const float* bf0   = (const float*)d_in[9];
    const float* Wf1   = (const float*)d_in[10];
    const float* bf1   = (const float*)d_in[11];
    const float* Wf2   = (const float*)d_in[12];
    const float* bf2   = (const float*)d_in[13];
    const float* Wf3   = (const float*)d_in[14];
    const float* bf3   = (const float*)d_in[15];
    float* out = (float*)d_out;

    char* ws = (char*)d_ws;
    uint16_t* Wt0hi  = (uint16_t*)(ws + 32768);               // 819200
    uint16_t* Wt0lo  = (uint16_t*)(ws + 851968);              // 819200
    uint16_t* Wt1hi  = (uint16_t*)(ws + 1671168);             // 131072
    uint16_t* Wt1lo  = (uint16_t*)(ws + 1802240);             // 131072
    uint16_t* Wt2hi  = (uint16_t*)(ws + 1933312);             // 131072
    uint16_t* Wt2lo  = (uint16_t*)(ws + 2064384);             // 131072
    uint16_t* DRhi   = (uint16_t*)(ws + 2195456);             // 26214400
    uint16_t* DRlo   = (uint16_t*)(ws + 28409856);            // 26214400
    uint16_t* hAhi   = (uint16_t*)(ws + 54624256);            // 4194304
    uint16_t* hAlo   = (uint16_t*)(ws + 58818560);            // 4194304
    uint16_t* hBhi   = (uint16_t*)(ws + 63012864);            // 4194304
    uint16_t* hBlo   = (uint16_t*)(ws + 67207168);            // 4194304
    // H2 (410KB) aliases hAhi: written by prep_h2, read by prep_tbl,
    // dead before epi1 writes hA.
    float* H2  = (float*)(ws + 54624256);
    // TBL (820KB) aliases hBhi: read by desc before gemm1 overwrites w/ Part1.
    float* TBL = (float*)(ws + 63012864);
    // Part1 (2x8.4MB fp32) aliases [hBhi..]: written by gemm1 (TBL dead),
    // read by epi1 (writes hA, disjoint), dead before epi2 writes hB.
    float* Part1 = (float*)(ws + 63012864);
    // Part2 aliases the DR region (dead after gemm1 reads it).
    float* Part2 = (float*)(ws + 2195456);

    prep_h2_kernel<<<401, 256, 0, stream>>>(We0, be0, We1, be1, H2);
    prep_tbl_kernel<<<801, 256, 0, stream>>>(H2, We2, be2, TBL);
    prep_wt_kernel<<<1600, 256, 0, stream>>>(Wf0, Wt0hi, Wt0lo, 1600, 1600);
    prep_wt_kernel<<<256, 256, 0, stream>>>(Wf1, Wt1hi, Wt1lo, 240, 256);
    prep_wt_kernel<<<256, 256, 0, stream>>>(Wf2, Wt2hi, Wt2lo, 240, 256);

    desc_kernel<<<NB * NN, 256, 0, stream>>>(dR, neigh, TBL, DRhi, DRlo);

    gemm_part<1600, 2><<<dim3(128, 4, 2), 256, 0, stream>>>(DRhi, DRlo, Wt0hi, Wt0lo, Part1);
    gemm_epi<<<2048, 256, 0, stream>>>(Part1, bf0, hAhi, hAlo);
    gemm_part<256, 2><<<dim3(128, 4, 2), 256, 0, stream>>>(hAhi, hAlo, Wt1hi, Wt1lo, Part2);
    gemm_epi<<<2048, 256, 0, stream>>>(Part2, bf1, hBhi, hBlo);
    gemm_part<256, 2><<<dim3(128, 4, 2), 256, 0, stream>>>(hBhi, hBlo, Wt2hi, Wt2lo, Part2);
    gemm_epi<<<2048, 256, 0, stream>>>(Part2, bf2, hAhi, hAlo);

    final_dot_kernel<<<NB * NN / 4, 256, 0, stream>>>(hAhi, hAlo, Wf3, bf3, out);
    etot_kernel<<<NB, 256, 0, stream>>>(out);
}

// Round 18
// 172.997 us; speedup vs baseline: 3.0596x; 1.0064x over previous
//
#include <hip/hip_runtime.h>
#include <hip/hip_bf16.h>
#include <math.h>
#include <stdint.h>

#define NB 4
#define NN 2048
#define NA 128
#define NK 2048                         /* table intervals; knots 0..NK */
#define RMINF 5.8f
#define RMAXF 6.0f
#define PI_OVER_DR 15.707963267948966f  /* pi / (RMAX-RMIN) */

typedef __attribute__((ext_vector_type(8))) short short8v;   // 8 bf16 (MFMA A/B frag)
typedef __attribute__((ext_vector_type(4))) float f32x4;     // MFMA C/D frag

// Exact tanh via exp: tanh(x) = 1 - 2/(e^{2x}+1). ~7 VALU inst, rel err ~1e-6.
__device__ __forceinline__ float fast_tanh(float x)
{
    x = fminf(fmaxf(x, -15.f), 15.f);
    float e = __expf(2.f * x);
    float r = __builtin_amdgcn_rcpf(e + 1.f);
    return fmaf(-2.f, r, 1.f);
}

__device__ __forceinline__ uint16_t bf16_of(float x)
{
    __hip_bfloat16 b = __float2bfloat16(x);
    return *(uint16_t*)&b;
}

__device__ __forceinline__ float bf16_to_f(uint16_t v)
{
    union { uint32_t u; float f; } c; c.u = ((uint32_t)v) << 16; return c.f;
}

// Fragment-major packed element offset for an MFMA-A/B-side matrix X[R][Ktot]:
// tile (16 r x 32 k) = 512 contiguous elems; within tile, lane-major per the
// 16x16x32 frag map (lane = (r&15) + kg*16, elems k = kg*8..kg*8+7).
__device__ __forceinline__ size_t packed_off(int r, int k, int Ktot)
{
    return ((size_t)((r >> 4) * (Ktot >> 5) + (k >> 5)) << 9)
         + (((r & 15) + (((k >> 3) & 3) << 4)) << 3) + (k & 7);
}

// S value for table knot (shared by both table kernels).
__device__ __forceinline__ float knot_S(int knot)
{
    float uu = (float)knot / (float)NK;
    return (knot == NK) ? 1e8f : uu / (1.f - uu);
}

// ---------------------------------------------------------------------------
// Table stage A: H2[knot][j] = tanh(be1[j] + sum_k tanh(S*We0[k]+be0[k])*We1[k][j])
// ---------------------------------------------------------------------------
__global__ void prep_h2_kernel(
    const float* __restrict__ We0, const float* __restrict__ be0,
    const float* __restrict__ We1, const float* __restrict__ be1,
    float* __restrict__ H2)
{
    int idx = blockIdx.x * 256 + threadIdx.x;
    if (idx >= (NK + 1) * 50) return;
    int knot = idx / 50, j = idx - knot * 50;
    float S = knot_S(knot);
    float acc = be1[j];
    #pragma unroll
    for (int k = 0; k < 25; ++k) {
        float h1k = fast_tanh(fmaf(S, We0[k], be0[k]));
        acc = fmaf(h1k, We1[k * 50 + j], acc);
    }
    H2[idx] = fast_tanh(acc);
}

// ---------------------------------------------------------------------------
// Table stage B: TBL[knot][j] = tanh(be2[j] + sum_k H2[knot][k]*We2[k][j]).
// ---------------------------------------------------------------------------
__global__ void prep_tbl_kernel(
    const float* __restrict__ H2,
    const float* __restrict__ We2, const float* __restrict__ be2,
    float* __restrict__ TBL)
{
    int idx = blockIdx.x * 256 + threadIdx.x;
    if (idx >= (NK + 1) * 100) return;
    int knot = idx / 100, j = idx - knot * 100;
    const float* h2 = H2 + knot * 50;
    float acc = be2[j];
    #pragma unroll
    for (int k = 0; k < 50; ++k)
        acc = fmaf(h2[k], We2[k * 100 + j], acc);
    TBL[idx] = fast_tanh(acc);
}

// ---------------------------------------------------------------------------
// Prep: fitting weight W [K][240] fp32 -> Wt hi/lo PACKED [256][KP] bf16.
// ---------------------------------------------------------------------------
__global__ void prep_wt_kernel(const float* __restrict__ W,
                               uint16_t* __restrict__ Whi,
                               uint16_t* __restrict__ Wlo,
                               int K, int KP)
{
    int idx = blockIdx.x * 256 + threadIdx.x;
    if (idx < 256 * KP) {
        int colN = idx / KP, k = idx - colN * KP;
        float v = (colN < 240 && k < K) ? W[k * 240 + colN] : 0.f;
        uint16_t hi = bf16_of(v);
        size_t off = packed_off(colN, k, KP);
        Whi[off] = hi;
        Wlo[off] = bf16_of(v - bf16_to_f(hi));
    }
}

// ---------------------------------------------------------------------------
// Descriptor kernel v18: j-pair gather + DEPTH-2 parity prefetch.
// Coverage = 8 waves/SIMD x ~32 cyc/iter ~ 256 > L2 latency; VGPR ~42 <= 64.
// ---------------------------------------------------------------------------
__global__ __launch_bounds__(256) void desc_kernel(
    const float* __restrict__ dR, const int* __restrict__ neigh,
    const float* __restrict__ TBL,
    uint16_t* __restrict__ DRhi, uint16_t* __restrict__ DRlo)
{
    const int bid = blockIdx.x;
    const int atom = (bid & 7) * 1024 + (bid >> 3);   // bijection on [0,8192)
    const int t = threadIdx.x;

    __shared__ float4 RiSh[128];
    __shared__ float2 IFSh[128];            // (frac, as_float(ia*100))
    __shared__ float  tmpPart[4][4][100];   // 6.4 KB
    __shared__ float  tmpBf[4][100];
    __shared__ unsigned long long balls[2];

    // ---- phase A: one thread per neighbor (t<128) ----
    float x = 0.f, y = 0.f, z = 0.f, S = 0.f, s_inv = 1.f;
    if (t < 128) {
        const int base = atom * NA;
        x = dR[(base + t) * 3 + 0];
        y = dR[(base + t) * 3 + 1];
        z = dR[(base + t) * 3 + 2];
        int nb = neigh[base + t];
        float Rij = x * x + y * y + z * z;      // squared distance (ref quirk)
        bool mask = nb > 0;
        bool mask_min = Rij < RMINF;
        float safe = (Rij > 0.f) ? Rij : 1.f;
        s_inv = 1.f / safe;
        float s_cos = 0.5f * cosf((Rij - RMINF) * PI_OVER_DR) + 0.5f;
        S = (mask && mask_min) ? s_inv
          : ((!mask_min && Rij < RMAXF) ? s_cos : 0.f);
        unsigned long long bal = __ballot(mask);
        if ((t & 63) == 0) balls[t >> 6] = bal;
    }
    __syncthreads();   // #1: balls visible

    if (t < 128) {
        unsigned long long nb0 = ~balls[0], nb1 = ~balls[1];
        int firstBad;
        if (nb0)       firstBad = __ffsll((long long)nb0) - 1;
        else if (nb1)  firstBad = 64 + __ffsll((long long)nb1) - 1;
        else           firstBad = 128;
        float f = (t < firstBad) ? (S * s_inv) : 0.f;
        RiSh[t] = make_float4(S, f * x, f * y, f * z);
        float uu = S / (1.f + S);               // match prep map exactly
        float pos = fminf(uu * (float)NK, (float)NK - 0.001f);
        float fi = floorf(pos);
        IFSh[t] = make_float2(pos - fi, __int_as_float((int)fi * 100));
    }
    __syncthreads();   // #2: RiSh + IFSh ready

    // ---- phase B: j-pair gather-contraction, depth-2 parity prefetch ----
    const int aq = t >> 6;          // 0..3 -> a-chunk of 32
    const int jp = t & 63;          // j-pair index, active < 50
    if (jp < 50) {
        const float* TBLp = TBL + jp * 2;
        const int a0 = aq * 32;

        float acc00 = 0.f, acc01 = 0.f;
        float acc10 = 0.f, acc11 = 0.f;
        float acc20 = 0.f, acc21 = 0.f;
        float acc30 = 0.f, acc31 = 0.f;

        // depth-2 prefetch: parity buffers for i and i+1
        float  fr[2];
        float2 T0[2], T1[2];
        {
            float2 if0 = IFSh[a0 + 0];
            float2 if1 = IFSh[a0 + 1];
            int ia0 = __float_as_int(if0.y);
            int ia1 = __float_as_int(if1.y);
            fr[0] = if0.x;  fr[1] = if1.x;
            T0[0] = *(const float2*)(TBLp + ia0);
            T1[0] = *(const float2*)(TBLp + ia0 + 100);
            T0[1] = *(const float2*)(TBLp + ia1);
            T1[1] = *(const float2*)(TBLp + ia1 + 100);
        }
        #pragma unroll
        for (int i = 0; i < 32; ++i) {
            const int b = i & 1;
            float  cf = fr[b];
            float2 c0 = T0[b], c1 = T1[b];
            if (i + 2 < 32) {
                float2 ifv = IFSh[a0 + i + 2];
                int ia = __float_as_int(ifv.y);
                fr[b] = ifv.x;
                T0[b] = *(const float2*)(TBLp + ia);
                T1[b] = *(const float2*)(TBLp + ia + 100);
            }
            float4 cri = RiSh[a0 + i];          // broadcast LDS read
            float g0 = fmaf(cf, c1.x - c0.x, c0.x);
            float g1 = fmaf(cf, c1.y - c0.y, c0.y);
            acc00 = fmaf(cri.x, g0, acc00); acc01 = fmaf(cri.x, g1, acc01);
            acc10 = fmaf(cri.y, g0, acc10); acc11 = fmaf(cri.y, g1, acc11);
            acc20 = fmaf(cri.z, g0, acc20); acc21 = fmaf(cri.z, g1, acc21);
            acc30 = fmaf(cri.w, g0, acc30); acc31 = fmaf(cri.w, g1, acc31);
        }
        *(float2*)&tmpPart[aq][0][jp * 2] = make_float2(acc00, acc01);
        *(float2*)&tmpPart[aq][1][jp * 2] = make_float2(acc10, acc11);
        *(float2*)&tmpPart[aq][2][jp * 2] = make_float2(acc20, acc21);
        *(float2*)&tmpPart[aq][3][jp * 2] = make_float2(acc30, acc31);
    }
    __syncthreads();   // #3

    // ---- reduce 4 a-chunks ----
    for (int idx = t; idx < 400; idx += 256) {
        int c = idx / 100, j = idx - c * 100;
        tmpBf[c][j] = tmpPart[0][c][j] + tmpPart[1][c][j]
                    + tmpPart[2][c][j] + tmpPart[3][c][j];
    }
    __syncthreads();   // #4

    // ---- phase C: DR[i][M] -> bf16 hi/lo PACKED; i split by half ----
    const int half = t >> 7;
    const int u = t & 127;
    if (u < 100) {
        float b0 = tmpBf[0][u];
        float b1 = tmpBf[1][u];
        float b2 = tmpBf[2][u];
        float b3 = tmpBf[3][u];
        const int i0 = half * 8;
        #pragma unroll
        for (int ii = 0; ii < 8; ++ii) {
            int i = i0 + ii;
            float v = tmpBf[0][i] * b0 + tmpBf[1][i] * b1
                    + tmpBf[2][i] * b2 + tmpBf[3][i] * b3;
            uint16_t hi = bf16_of(v);
            size_t off = packed_off(atom, i * 100 + u, 1600);
            DRhi[off] = hi;
            DRlo[off] = bf16_of(v - bf16_to_f(hi));
        }
    }
}

// ---------------------------------------------------------------------------
// GEMM partials from PACKED operands: Part[z][8192][256] (fp32, row-major).
// 256 thr = 4 waves (2mg x 2ng), per-wave 32x32, BM=BN=64.
// Grid (128, 4, KSPLIT) = 1024 blocks. Register double-buffer, fully unrolled.
// ---------------------------------------------------------------------------
template<int KP, int KSPLIT>
__global__ __launch_bounds__(256, 4) void gemm_part(
    const uint16_t* __restrict__ Ahi, const uint16_t* __restrict__ Alo,
    const uint16_t* __restrict__ Wthi, const uint16_t* __restrict__ Wtlo,
    float* __restrict__ Part)
{
    constexpr int KT = KP >> 5;              // total k-tiles
    constexpr int STEPS = KT / KSPLIT;       // k-tiles this chunk
    const int tid = threadIdx.x;
    const int wid = tid >> 6, lane = tid & 63;
    const int mg = wid >> 1, ng = wid & 1;
    const int mt0 = blockIdx.x * 4 + mg * 2;
    const int nt0 = blockIdx.y * 4 + ng * 2;
    const int kt0 = blockIdx.z * STEPS;

    const size_t aB0 = ((size_t)(mt0 + 0) * KT + kt0) * 512 + lane * 8;
    const size_t aB1 = ((size_t)(mt0 + 1) * KT + kt0) * 512 + lane * 8;
    const size_t bB0 = ((size_t)(nt0 + 0) * KT + kt0) * 512 + lane * 8;
    const size_t bB1 = ((size_t)(nt0 + 1) * KT + kt0) * 512 + lane * 8;

    f32x4 acc[2][2];
    #pragma unroll
    for (int m = 0; m < 2; ++m)
        #pragma unroll
        for (int n = 0; n < 2; ++n) acc[m][n] = (f32x4){0.f, 0.f, 0.f, 0.f};

    short8v f[2][8];

#define LOADSET(B, S) do {                                       \
        f[B][0] = *(const short8v*)(Ahi  + aB0 + (S) * 512);     \
        f[B][1] = *(const short8v*)(Ahi  + aB1 + (S) * 512);     \
        f[B][2] = *(const short8v*)(Alo  + aB0 + (S) * 512);     \
        f[B][3] = *(const short8v*)(Alo  + aB1 + (S) * 512);     \
        f[B][4] = *(const short8v*)(Wthi + bB0 + (S) * 512);     \
        f[B][5] = *(const short8v*)(Wthi + bB1 + (S) * 512);     \
        f[B][6] = *(const short8v*)(Wtlo + bB0 + (S) * 512);     \
        f[B][7] = *(const short8v*)(Wtlo + bB1 + (S) * 512);     \
    } while (0)

    LOADSET(0, 0);
    #pragma unroll
    for (int s = 0; s < STEPS; ++s) {
        const int b = s & 1;
        if (s + 1 < STEPS) LOADSET(b ^ 1, s + 1);
        #pragma unroll
        for (int m = 0; m < 2; ++m)
            #pragma unroll
            for (int n = 0; n < 2; ++n) {
                acc[m][n] = __builtin_amdgcn_mfma_f32_16x16x32_bf16(f[b][m],     f[b][4 + n], acc[m][n], 0, 0, 0);
                acc[m][n] = __builtin_amdgcn_mfma_f32_16x16x32_bf16(f[b][m],     f[b][6 + n], acc[m][n], 0, 0, 0);
                acc[m][n] = __builtin_amdgcn_mfma_f32_16x16x32_bf16(f[b][2 + m], f[b][4 + n], acc[m][n], 0, 0, 0);
            }
    }
#undef LOADSET

    const int ar = lane & 15, kg = lane >> 4;
    float* pp = Part + (size_t)blockIdx.z * (8192 * 256);
    #pragma unroll
    for (int m = 0; m < 2; ++m)
        #pragma unroll
        for (int n = 0; n < 2; ++n)
            #pragma unroll
            for (int r = 0; r < 4; ++r)
                pp[(size_t)((mt0 + m) * 16 + kg * 4 + r) * 256 + (nt0 + n) * 16 + ar] = acc[m][n][r];
}

// ---------------------------------------------------------------------------
// Epilogue: O = tanh(sum_z Part[z] + bias) -> bf16 hi/lo PACKED (Ktot=256).
// XCD-swizzled so the 4 blocks covering each 16-row packed tile share an L2.
// ---------------------------------------------------------------------------
__global__ __launch_bounds__(256) void gemm_epi(
    const float* __restrict__ Part, const float* __restrict__ bias,
    uint16_t* __restrict__ Ohi, uint16_t* __restrict__ Olo)
{
    int g = (blockIdx.x & 7) * 256 + (blockIdx.x >> 3);   // bijection on [0,2048)
    int idx0 = g * 1024 + threadIdx.x;
    #pragma unroll
    for (int it = 0; it < 4; ++it) {
        int idx = idx0 + it * 256;
        int col = idx & 255;
        int row = idx >> 8;
        float s = Part[idx] + Part[idx + 8192 * 256];
        float v = (col < 240) ? fast_tanh(s + bias[col]) : 0.f;
        uint16_t hi = bf16_of(v);
        size_t off = packed_off(row, col, 256);
        Ohi[off] = hi;
        Olo[off] = bf16_of(v - bf16_to_f(hi));
    }
}

// ---------------------------------------------------------------------------
// Ei = (h_hi+h_lo) @ Wf3 + bf3 : one wave per atom; H is PACKED (Ktot=256).
// ---------------------------------------------------------------------------
__global__ __launch_bounds__(256) void final_dot_kernel(
    const uint16_t* __restrict__ Hhi, const uint16_t* __restrict__ Hlo,
    const float* __restrict__ Wf3, const float* __restrict__ bf3,
    float* __restrict__ out)
{
    int wave = threadIdx.x >> 6, lane = threadIdx.x & 63;
    int atom = blockIdx.x * 4 + wave;
    float v = 0.f;
    if (lane < 60) {
        size_t off = packed_off(atom, lane * 4, 256);
        ushort4 h4 = *(const ushort4*)(Hhi + off);
        ushort4 l4 = *(const ushort4*)(Hlo + off);
        float4 w = *(const float4*)&Wf3[lane * 4];
        v = (bf16_to_f(h4.x) + bf16_to_f(l4.x)) * w.x
          + (bf16_to_f(h4.y) + bf16_to_f(l4.y)) * w.y
          + (bf16_to_f(h4.z) + bf16_to_f(l4.z)) * w.z
          + (bf16_to_f(h4.w) + bf16_to_f(l4.w)) * w.w;
    }
    #pragma unroll
    for (int off = 32; off; off >>= 1) v += __shfl_down(v, off, 64);
    if (lane == 0) out[4 + atom] = v + bf3[0];
}

__global__ __launch_bounds__(256) void etot_kernel(float* __restrict__ out)
{
    __shared__ float red[256];
    int b = blockIdx.x, t = threadIdx.x;
    float s = 0.f;
    for (int i = t; i < NN; i += 256) s += out[4 + b * NN + i];
    red[t] = s;
    __syncthreads();
    for (int w = 128; w; w >>= 1) {
        if (t < w) red[t] += red[t + w];
        __syncthreads();
    }
    if (t == 0) out[b] = red[0];
}

// ---------------------------------------------------------------------------
extern "C" void kernel_launch(void* const* d_in, const int* in_sizes, int n_in,
                              void* d_out, int out_size, void* d_ws, size_t ws_size,
                              hipStream_t stream)
{
    const float* dR    = (const float*)d_in[0];
    const int*   neigh = (const int*)d_in[1];
    const float* We0   = (const float*)d_in[2];
    const float* be0   = (const float*)d_in[3];
    const float* We1   = (const float*)d_in[4];
    const float* be1   = (const float*)d_in[5];
    const float* We2   = (const float*)d_in[6];
    const float* be2   = (const float*)d_in[7];
    const float* Wf0   = (const float*)d_in[8];
    const float* bf0   = (const float*)d_in[9];
    const float* Wf1   = (const float*)d_in[10];
    const float* bf1   = (const float*)d_in[11];
    const float* Wf2   = (const float*)d_in[12];
    const float* bf2   = (const float*)d_in[13];
    const float* Wf3   = (const float*)d_in[14];
    const float* bf3   = (const float*)d_in[15];
    float* out = (float*)d_out;

    char* ws = (char*)d_ws;
    uint16_t* Wt0hi  = (uint16_t*)(ws + 32768);               // 819200
    uint16_t* Wt0lo  = (uint16_t*)(ws + 851968);              // 819200
    uint16_t* Wt1hi  = (uint16_t*)(ws + 1671168);             // 131072
    uint16_t* Wt1lo  = (uint16_t*)(ws + 1802240);             // 131072
    uint16_t* Wt2hi  = (uint16_t*)(ws + 1933312);             // 131072
    uint16_t* Wt2lo  = (uint16_t*)(ws + 2064384);             // 131072
    uint16_t* DRhi   = (uint16_t*)(ws + 2195456);             // 26214400
    uint16_t* DRlo   = (uint16_t*)(ws + 28409856);            // 26214400
    uint16_t* hAhi   = (uint16_t*)(ws + 54624256);            // 4194304
    uint16_t* hAlo   = (uint16_t*)(ws + 58818560);            // 4194304
    uint16_t* hBhi   = (uint16_t*)(ws + 63012864);            // 4194304
    uint16_t* hBlo   = (uint16_t*)(ws + 67207168);            // 4194304
    // H2 (410KB) aliases hAhi: written by prep_h2, read by prep_tbl,
    // dead before epi1 writes hA.
    float* H2  = (float*)(ws + 54624256);
    // TBL (820KB) aliases hBhi: read by desc before gemm1 overwrites w/ Part1.
    float* TBL = (float*)(ws + 63012864);
    // Part1 (2x8.4MB fp32) aliases [hBhi..]: written by gemm1 (TBL dead),
    // read by epi1 (writes hA, disjoint), dead before epi2 writes hB.
    float* Part1 = (float*)(ws + 63012864);
    // Part2 aliases the DR region (dead after gemm1 reads it).
    float* Part2 = (float*)(ws + 2195456);

    prep_h2_kernel<<<401, 256, 0, stream>>>(We0, be0, We1, be1, H2);
    prep_tbl_kernel<<<801, 256, 0, stream>>>(H2, We2, be2, TBL);
    prep_wt_kernel<<<1600, 256, 0, stream>>>(Wf0, Wt0hi, Wt0lo, 1600, 1600);
    prep_wt_kernel<<<256, 256, 0, stream>>>(Wf1, Wt1hi, Wt1lo, 240, 256);
    prep_wt_kernel<<<256, 256, 0, stream>>>(Wf2, Wt2hi, Wt2lo, 240, 256);

    desc_kernel<<<NB * NN, 256, 0, stream>>>(dR, neigh, TBL, DRhi, DRlo);

    gemm_part<1600, 2><<<dim3(128, 4, 2), 256, 0, stream>>>(DRhi, DRlo, Wt0hi, Wt0lo, Part1);
    gemm_epi<<<2048, 256, 0, stream>>>(Part1, bf0, hAhi, hAlo);
    gemm_part<256, 2><<<dim3(128, 4, 2), 256, 0, stream>>>(hAhi, hAlo, Wt1hi, Wt1lo, Part2);
    gemm_epi<<<2048, 256, 0, stream>>>(Part2, bf1, hBhi, hBlo);
    gemm_part<256, 2><<<dim3(128, 4, 2), 256, 0, stream>>>(hBhi, hBlo, Wt2hi, Wt2lo, Part2);
    gemm_epi<<<2048, 256, 0, stream>>>(Part2, bf2, hAhi, hAlo);

    final_dot_kernel<<<NB * NN / 4, 256, 0, stream>>>(hAhi, hAlo, Wf3, bf3, out);
    etot_kernel<<<NB, 256, 0, stream>>>(out);
}

// Round 19
// 144.347 us; speedup vs baseline: 3.6669x; 1.1985x over previous
//
#include <hip/hip_runtime.h>
#include <hip/hip_bf16.h>
#include <math.h>
#include <stdint.h>

#define NB 4
#define NN 2048
#define NA 128
#define NK 2048                         /* table intervals; knots 0..NK */
#define RMINF 5.8f
#define RMAXF 6.0f
#define PI_OVER_DR 15.707963267948966f  /* pi / (RMAX-RMIN) */

typedef __attribute__((ext_vector_type(8))) short short8v;   // 8 bf16 (MFMA A/B frag)
typedef __attribute__((ext_vector_type(4))) float f32x4;     // MFMA C/D frag

// Exact tanh via exp: tanh(x) = 1 - 2/(e^{2x}+1). ~7 VALU inst, rel err ~1e-6.
__device__ __forceinline__ float fast_tanh(float x)
{
    x = fminf(fmaxf(x, -15.f), 15.f);
    float e = __expf(2.f * x);
    float r = __builtin_amdgcn_rcpf(e + 1.f);
    return fmaf(-2.f, r, 1.f);
}

__device__ __forceinline__ uint16_t bf16_of(float x)
{
    __hip_bfloat16 b = __float2bfloat16(x);
    return *(uint16_t*)&b;
}

__device__ __forceinline__ float bf16_to_f(uint16_t v)
{
    union { uint32_t u; float f; } c; c.u = ((uint32_t)v) << 16; return c.f;
}

// Fragment-major packed element offset for an MFMA-A/B-side matrix X[R][Ktot]:
// tile (16 r x 32 k) = 512 contiguous elems; within tile, lane-major per the
// 16x16x32 frag map (lane = (r&15) + kg*16, elems k = kg*8..kg*8+7).
__device__ __forceinline__ size_t packed_off(int r, int k, int Ktot)
{
    return ((size_t)((r >> 4) * (Ktot >> 5) + (k >> 5)) << 9)
         + (((r & 15) + (((k >> 3) & 3) << 4)) << 3) + (k & 7);
}

// S value for table knot (shared by both table kernels).
__device__ __forceinline__ float knot_S(int knot)
{
    float uu = (float)knot / (float)NK;
    return (knot == NK) ? 1e8f : uu / (1.f - uu);
}

// ---------------------------------------------------------------------------
// Table stage A: H2[knot][j] = tanh(be1[j] + sum_k tanh(S*We0[k]+be0[k])*We1[k][j])
// ---------------------------------------------------------------------------
__global__ void prep_h2_kernel(
    const float* __restrict__ We0, const float* __restrict__ be0,
    const float* __restrict__ We1, const float* __restrict__ be1,
    float* __restrict__ H2)
{
    int idx = blockIdx.x * 256 + threadIdx.x;
    if (idx >= (NK + 1) * 50) return;
    int knot = idx / 50, j = idx - knot * 50;
    float S = knot_S(knot);
    float acc = be1[j];
    #pragma unroll
    for (int k = 0; k < 25; ++k) {
        float h1k = fast_tanh(fmaf(S, We0[k], be0[k]));
        acc = fmaf(h1k, We1[k * 50 + j], acc);
    }
    H2[idx] = fast_tanh(acc);
}

// ---------------------------------------------------------------------------
// Table stage B: TBL[knot][j] = tanh(be2[j] + sum_k H2[knot][k]*We2[k][j]).
// ---------------------------------------------------------------------------
__global__ void prep_tbl_kernel(
    const float* __restrict__ H2,
    const float* __restrict__ We2, const float* __restrict__ be2,
    float* __restrict__ TBL)
{
    int idx = blockIdx.x * 256 + threadIdx.x;
    if (idx >= (NK + 1) * 100) return;
    int knot = idx / 100, j = idx - knot * 100;
    const float* h2 = H2 + knot * 50;
    float acc = be2[j];
    #pragma unroll
    for (int k = 0; k < 50; ++k)
        acc = fmaf(h2[k], We2[k * 100 + j], acc);
    TBL[idx] = fast_tanh(acc);
}

// ---------------------------------------------------------------------------
// Prep: fitting weight W [K][240] fp32 -> Wt hi/lo PACKED [256][KP] bf16.
// ---------------------------------------------------------------------------
__global__ void prep_wt_kernel(const float* __restrict__ W,
                               uint16_t* __restrict__ Whi,
                               uint16_t* __restrict__ Wlo,
                               int K, int KP)
{
    int idx = blockIdx.x * 256 + threadIdx.x;
    if (idx < 256 * KP) {
        int colN = idx / KP, k = idx - colN * KP;
        float v = (colN < 240 && k < K) ? W[k * 240 + colN] : 0.f;
        uint16_t hi = bf16_of(v);
        size_t off = packed_off(colN, k, KP);
        Whi[off] = hi;
        Wlo[off] = bf16_of(v - bf16_to_f(hi));
    }
}

// ---------------------------------------------------------------------------
// Descriptor kernel v19 (= R14 structure, best measured): j-quad gather,
// depth-1 prefetch; DR written as SINGLE bf16 plane (hi only: WRITE halves,
// A-side quantization err ~0.4% rel, same magnitude as R1's measured 4.0).
// ---------------------------------------------------------------------------
__global__ __launch_bounds__(256) void desc_kernel(
    const float* __restrict__ dR, const int* __restrict__ neigh,
    const float* __restrict__ TBL,
    uint16_t* __restrict__ DRhi)
{
    const int bid = blockIdx.x;
    const int atom = (bid & 7) * 1024 + (bid >> 3);   // bijection on [0,8192)
    const int t = threadIdx.x;

    __shared__ float4 RiSh[128];
    __shared__ float2 IFSh[128];            // (frac, as_float(ia*100))
    __shared__ float  tmpPart[8][4][100];   // 12.8 KB
    __shared__ float  tmpBf[4][100];
    __shared__ unsigned long long balls[2];

    // ---- phase A: one thread per neighbor (t<128) ----
    float x = 0.f, y = 0.f, z = 0.f, S = 0.f, s_inv = 1.f;
    if (t < 128) {
        const int base = atom * NA;
        x = dR[(base + t) * 3 + 0];
        y = dR[(base + t) * 3 + 1];
        z = dR[(base + t) * 3 + 2];
        int nb = neigh[base + t];
        float Rij = x * x + y * y + z * z;      // squared distance (ref quirk)
        bool mask = nb > 0;
        bool mask_min = Rij < RMINF;
        float safe = (Rij > 0.f) ? Rij : 1.f;
        s_inv = 1.f / safe;
        float s_cos = 0.5f * cosf((Rij - RMINF) * PI_OVER_DR) + 0.5f;
        S = (mask && mask_min) ? s_inv
          : ((!mask_min && Rij < RMAXF) ? s_cos : 0.f);
        unsigned long long bal = __ballot(mask);
        if ((t & 63) == 0) balls[t >> 6] = bal;
    }
    __syncthreads();   // #1: balls visible

    if (t < 128) {
        unsigned long long nb0 = ~balls[0], nb1 = ~balls[1];
        int firstBad;
        if (nb0)       firstBad = __ffsll((long long)nb0) - 1;
        else if (nb1)  firstBad = 64 + __ffsll((long long)nb1) - 1;
        else           firstBad = 128;
        float f = (t < firstBad) ? (S * s_inv) : 0.f;
        RiSh[t] = make_float4(S, f * x, f * y, f * z);
        float uu = S / (1.f + S);               // match prep map exactly
        float pos = fminf(uu * (float)NK, (float)NK - 0.001f);
        float fi = floorf(pos);
        IFSh[t] = make_float2(pos - fi, __int_as_float((int)fi * 100));
    }
    __syncthreads();   // #2: RiSh + IFSh ready

    // ---- phase B: j-quad gather-contraction (R14 best) ----
    const int aq = t >> 5;          // 0..7 -> a-chunk of 16
    const int jq = t & 31;          // j-quad index, active < 25
    if (jq < 25) {
        const float* TBLq = TBL + jq * 4;
        const int a0 = aq * 16;
        float acc00 = 0.f, acc01 = 0.f, acc02 = 0.f, acc03 = 0.f;
        float acc10 = 0.f, acc11 = 0.f, acc12 = 0.f, acc13 = 0.f;
        float acc20 = 0.f, acc21 = 0.f, acc22 = 0.f, acc23 = 0.f;
        float acc30 = 0.f, acc31 = 0.f, acc32 = 0.f, acc33 = 0.f;

        // depth-1 prefetch
        float2 ifv = IFSh[a0];
        float4 ri  = RiSh[a0];
        int    ia  = __float_as_int(ifv.y);
        float4 t0  = *(const float4*)(TBLq + ia);
        float4 t1  = *(const float4*)(TBLq + ia + 100);
        #pragma unroll
        for (int i = 0; i < 16; ++i) {
            float  cf = ifv.x;
            float4 cri = ri, c0 = t0, c1 = t1;
            if (i + 1 < 16) {
                float2 nifv = IFSh[a0 + i + 1];
                ri = RiSh[a0 + i + 1];
                ia = __float_as_int(nifv.y);
                t0 = *(const float4*)(TBLq + ia);
                t1 = *(const float4*)(TBLq + ia + 100);
                ifv = nifv;
            }
            float g0 = fmaf(cf, c1.x - c0.x, c0.x);
            float g1 = fmaf(cf, c1.y - c0.y, c0.y);
            float g2 = fmaf(cf, c1.z - c0.z, c0.z);
            float g3 = fmaf(cf, c1.w - c0.w, c0.w);
            acc00 = fmaf(cri.x, g0, acc00); acc01 = fmaf(cri.x, g1, acc01);
            acc02 = fmaf(cri.x, g2, acc02); acc03 = fmaf(cri.x, g3, acc03);
            acc10 = fmaf(cri.y, g0, acc10); acc11 = fmaf(cri.y, g1, acc11);
            acc12 = fmaf(cri.y, g2, acc12); acc13 = fmaf(cri.y, g3, acc13);
            acc20 = fmaf(cri.z, g0, acc20); acc21 = fmaf(cri.z, g1, acc21);
            acc22 = fmaf(cri.z, g2, acc22); acc23 = fmaf(cri.z, g3, acc23);
            acc30 = fmaf(cri.w, g0, acc30); acc31 = fmaf(cri.w, g1, acc31);
            acc32 = fmaf(cri.w, g2, acc32); acc33 = fmaf(cri.w, g3, acc33);
        }
        *(float4*)&tmpPart[aq][0][jq * 4] = make_float4(acc00, acc01, acc02, acc03);
        *(float4*)&tmpPart[aq][1][jq * 4] = make_float4(acc10, acc11, acc12, acc13);
        *(float4*)&tmpPart[aq][2][jq * 4] = make_float4(acc20, acc21, acc22, acc23);
        *(float4*)&tmpPart[aq][3][jq * 4] = make_float4(acc30, acc31, acc32, acc33);
    }
    __syncthreads();   // #3

    // ---- reduce 8 a-chunks ----
    for (int idx = t; idx < 400; idx += 256) {
        int c = idx / 100, j = idx - c * 100;
        float s = tmpPart[0][c][j] + tmpPart[1][c][j]
                + tmpPart[2][c][j] + tmpPart[3][c][j]
                + tmpPart[4][c][j] + tmpPart[5][c][j]
                + tmpPart[6][c][j] + tmpPart[7][c][j];
        tmpBf[c][j] = s;
    }
    __syncthreads();   // #4

    // ---- phase C: DR[i][M] -> single bf16 plane PACKED; i split by half ----
    const int half = t >> 7;
    const int u = t & 127;
    if (u < 100) {
        float b0 = tmpBf[0][u];
        float b1 = tmpBf[1][u];
        float b2 = tmpBf[2][u];
        float b3 = tmpBf[3][u];
        const int i0 = half * 8;
        #pragma unroll
        for (int ii = 0; ii < 8; ++ii) {
            int i = i0 + ii;
            float v = tmpBf[0][i] * b0 + tmpBf[1][i] * b1
                    + tmpBf[2][i] * b2 + tmpBf[3][i] * b3;
            DRhi[packed_off(atom, i * 100 + u, 1600)] = bf16_of(v);
        }
    }
}

// ---------------------------------------------------------------------------
// GEMM partials from PACKED operands: Part[z][8192][256] (fp32, row-major).
// ALO=false: A is single bf16 plane (2-term: ah*bh + ah*bl).
// ALO=true : A split hi/lo (3-term).
// ---------------------------------------------------------------------------
template<int KP, int KSPLIT, bool ALO>
__global__ __launch_bounds__(256, 4) void gemm_part(
    const uint16_t* __restrict__ Ahi, const uint16_t* __restrict__ Alo,
    const uint16_t* __restrict__ Wthi, const uint16_t* __restrict__ Wtlo,
    float* __restrict__ Part)
{
    constexpr int KT = KP >> 5;              // total k-tiles
    constexpr int STEPS = KT / KSPLIT;       // k-tiles this chunk
    const int tid = threadIdx.x;
    const int wid = tid >> 6, lane = tid & 63;
    const int mg = wid >> 1, ng = wid & 1;
    const int mt0 = blockIdx.x * 4 + mg * 2;
    const int nt0 = blockIdx.y * 4 + ng * 2;
    const int kt0 = blockIdx.z * STEPS;

    const size_t aB0 = ((size_t)(mt0 + 0) * KT + kt0) * 512 + lane * 8;
    const size_t aB1 = ((size_t)(mt0 + 1) * KT + kt0) * 512 + lane * 8;
    const size_t bB0 = ((size_t)(nt0 + 0) * KT + kt0) * 512 + lane * 8;
    const size_t bB1 = ((size_t)(nt0 + 1) * KT + kt0) * 512 + lane * 8;

    f32x4 acc[2][2];
    #pragma unroll
    for (int m = 0; m < 2; ++m)
        #pragma unroll
        for (int n = 0; n < 2; ++n) acc[m][n] = (f32x4){0.f, 0.f, 0.f, 0.f};

    short8v f[2][8];

#define LOADSET(B, S) do {                                           \
        f[B][0] = *(const short8v*)(Ahi  + aB0 + (S) * 512);         \
        f[B][1] = *(const short8v*)(Ahi  + aB1 + (S) * 512);         \
        if (ALO) {                                                   \
            f[B][2] = *(const short8v*)(Alo + aB0 + (S) * 512);      \
            f[B][3] = *(const short8v*)(Alo + aB1 + (S) * 512);      \
        }                                                            \
        f[B][4] = *(const short8v*)(Wthi + bB0 + (S) * 512);         \
        f[B][5] = *(const short8v*)(Wthi + bB1 + (S) * 512);         \
        f[B][6] = *(const short8v*)(Wtlo + bB0 + (S) * 512);         \
        f[B][7] = *(const short8v*)(Wtlo + bB1 + (S) * 512);         \
    } while (0)

    LOADSET(0, 0);
    #pragma unroll
    for (int s = 0; s < STEPS; ++s) {
        const int b = s & 1;
        if (s + 1 < STEPS) LOADSET(b ^ 1, s + 1);
        #pragma unroll
        for (int m = 0; m < 2; ++m)
            #pragma unroll
            for (int n = 0; n < 2; ++n) {
                acc[m][n] = __builtin_amdgcn_mfma_f32_16x16x32_bf16(f[b][m], f[b][4 + n], acc[m][n], 0, 0, 0);
                acc[m][n] = __builtin_amdgcn_mfma_f32_16x16x32_bf16(f[b][m], f[b][6 + n], acc[m][n], 0, 0, 0);
                if (ALO)
                    acc[m][n] = __builtin_amdgcn_mfma_f32_16x16x32_bf16(f[b][2 + m], f[b][4 + n], acc[m][n], 0, 0, 0);
            }
    }
#undef LOADSET

    const int ar = lane & 15, kg = lane >> 4;
    float* pp = Part + (size_t)blockIdx.z * (8192 * 256);
    #pragma unroll
    for (int m = 0; m < 2; ++m)
        #pragma unroll
        for (int n = 0; n < 2; ++n)
            #pragma unroll
            for (int r = 0; r < 4; ++r)
                pp[(size_t)((mt0 + m) * 16 + kg * 4 + r) * 256 + (nt0 + n) * 16 + ar] = acc[m][n][r];
}

// ---------------------------------------------------------------------------
// Epilogue: O = tanh(sum_z Part[z] + bias) -> bf16 hi/lo PACKED (Ktot=256).
// XCD-swizzled so the 4 blocks covering each 16-row packed tile share an L2.
// ---------------------------------------------------------------------------
__global__ __launch_bounds__(256) void gemm_epi(
    const float* __restrict__ Part, const float* __restrict__ bias,
    uint16_t* __restrict__ Ohi, uint16_t* __restrict__ Olo)
{
    int g = (blockIdx.x & 7) * 256 + (blockIdx.x >> 3);   // bijection on [0,2048)
    int idx0 = g * 1024 + threadIdx.x;
    #pragma unroll
    for (int it = 0; it < 4; ++it) {
        int idx = idx0 + it * 256;
        int col = idx & 255;
        int row = idx >> 8;
        float s = Part[idx] + Part[idx + 8192 * 256];
        float v = (col < 240) ? fast_tanh(s + bias[col]) : 0.f;
        uint16_t hi = bf16_of(v);
        size_t off = packed_off(row, col, 256);
        Ohi[off] = hi;
        Olo[off] = bf16_of(v - bf16_to_f(hi));
    }
}

// ---------------------------------------------------------------------------
// Ei = (h_hi+h_lo) @ Wf3 + bf3 : one wave per atom; H is PACKED (Ktot=256).
// ---------------------------------------------------------------------------
__global__ __launch_bounds__(256) void final_dot_kernel(
    const uint16_t* __restrict__ Hhi, const uint16_t* __restrict__ Hlo,
    const float* __restrict__ Wf3, const float* __restrict__ bf3,
    float* __restrict__ out)
{
    int wave = threadIdx.x >> 6, lane = threadIdx.x & 63;
    int atom = blockIdx.x * 4 + wave;
    float v = 0.f;
    if (lane < 60) {
        size_t off = packed_off(atom, lane * 4, 256);
        ushort4 h4 = *(const ushort4*)(Hhi + off);
        ushort4 l4 = *(const ushort4*)(Hlo + off);
        float4 w = *(const float4*)&Wf3[lane * 4];
        v = (bf16_to_f(h4.x) + bf16_to_f(l4.x)) * w.x
          + (bf16_to_f(h4.y) + bf16_to_f(l4.y)) * w.y
          + (bf16_to_f(h4.z) + bf16_to_f(l4.z)) * w.z
          + (bf16_to_f(h4.w) + bf16_to_f(l4.w)) * w.w;
    }
    #pragma unroll
    for (int off = 32; off; off >>= 1) v += __shfl_down(v, off, 64);
    if (lane == 0) out[4 + atom] = v + bf3[0];
}

__global__ __launch_bounds__(256) void etot_kernel(float* __restrict__ out)
{
    __shared__ float red[256];
    int b = blockIdx.x, t = threadIdx.x;
    float s = 0.f;
    for (int i = t; i < NN; i += 256) s += out[4 + b * NN + i];
    red[t] = s;
    __syncthreads();
    for (int w = 128; w; w >>= 1) {
        if (t < w) red[t] += red[t + w];
        __syncthreads();
    }
    if (t == 0) out[b] = red[0];
}

// ---------------------------------------------------------------------------
extern "C" void kernel_launch(void* const* d_in, const int* in_sizes, int n_in,
                              void* d_out, int out_size, void* d_ws, size_t ws_size,
                              hipStream_t stream)
{
    const float* dR    = (const float*)d_in[0];
    const int*   neigh = (const int*)d_in[1];
    const float* We0   = (const float*)d_in[2];
    const float* be0   = (const float*)d_in[3];
    const float* We1   = (const float*)d_in[4];
    const float* be1   = (const float*)d_in[5];
    const float* We2   = (const float*)d_in[6];
    const float* be2   = (const float*)d_in[7];
    const float* Wf0   = (const float*)d_in[8];
    const float* bf0   = (const float*)d_in[9];
    const float* Wf1   = (const float*)d_in[10];
    const float* bf1   = (const float*)d_in[11];
    const float* Wf2   = (const float*)d_in[12];
    const float* bf2   = (const float*)d_in[13];
    const float* Wf3   = (const float*)d_in[14];
    const float* bf3   = (const float*)d_in[15];
    float* out = (float*)d_out;

    char* ws = (char*)d_ws;
    uint16_t* Wt0hi  = (uint16_t*)(ws + 32768);               // 819200
    uint16_t* Wt0lo  = (uint16_t*)(ws + 851968);              // 819200
    uint16_t* Wt1hi  = (uint16_t*)(ws + 1671168);             // 131072
    uint16_t* Wt1lo  = (uint16_t*)(ws + 1802240);             // 131072
    uint16_t* Wt2hi  = (uint16_t*)(ws + 1933312);             // 131072
    uint16_t* Wt2lo  = (uint16_t*)(ws + 2064384);             // 131072
    uint16_t* DRhi   = (uint16_t*)(ws + 2195456);             // 26214400
    uint16_t* hAhi   = (uint16_t*)(ws + 54624256);            // 4194304
    uint16_t* hAlo   = (uint16_t*)(ws + 58818560);            // 4194304
    uint16_t* hBhi   = (uint16_t*)(ws + 63012864);            // 4194304
    uint16_t* hBlo   = (uint16_t*)(ws + 67207168);            // 4194304
    // H2 (410KB) aliases hAhi: written by prep_h2, read by prep_tbl,
    // dead before epi1 writes hA.
    float* H2  = (float*)(ws + 54624256);
    // TBL (820KB) aliases hBhi: read by desc before gemm1 overwrites w/ Part1.
    float* TBL = (float*)(ws + 63012864);
    // Part1 (2x8.4MB fp32) aliases [hBhi..]: written by gemm1 (TBL dead),
    // read by epi1 (writes hA, disjoint), dead before epi2 writes hB.
    float* Part1 = (float*)(ws + 63012864);
    // Part2 aliases the DR region (dead after gemm1 reads it).
    float* Part2 = (float*)(ws + 2195456);

    prep_h2_kernel<<<401, 256, 0, stream>>>(We0, be0, We1, be1, H2);
    prep_tbl_kernel<<<801, 256, 0, stream>>>(H2, We2, be2, TBL);
    prep_wt_kernel<<<1600, 256, 0, stream>>>(Wf0, Wt0hi, Wt0lo, 1600, 1600);
    prep_wt_kernel<<<256, 256, 0, stream>>>(Wf1, Wt1hi, Wt1lo, 240, 256);
    prep_wt_kernel<<<256, 256, 0, stream>>>(Wf2, Wt2hi, Wt2lo, 240, 256);

    desc_kernel<<<NB * NN, 256, 0, stream>>>(dR, neigh, TBL, DRhi);

    gemm_part<1600, 2, false><<<dim3(128, 4, 2), 256, 0, stream>>>(DRhi, DRhi, Wt0hi, Wt0lo, Part1);
    gemm_epi<<<2048, 256, 0, stream>>>(Part1, bf0, hAhi, hAlo);
    gemm_part<256, 2, true><<<dim3(128, 4, 2), 256, 0, stream>>>(hAhi, hAlo, Wt1hi, Wt1lo, Part2);
    gemm_epi<<<2048, 256, 0, stream>>>(Part2, bf1, hBhi, hBlo);
    gemm_part<256, 2, true><<<dim3(128, 4, 2), 256, 0, stream>>>(hBhi, hBlo, Wt2hi, Wt2lo, Part2);
    gemm_epi<<<2048, 256, 0, stream>>>(Part2, bf2, hAhi, hAlo);

    final_dot_kernel<<<NB * NN / 4, 256, 0, stream>>>(hAhi, hAlo, Wf3, bf3, out);
    etot_kernel<<<NB, 256, 0, stream>>>(out);
}

// Round 20
// 133.820 us; speedup vs baseline: 3.9553x; 1.0787x over previous
//
#include <hip/hip_runtime.h>
#include <hip/hip_bf16.h>
#include <math.h>
#include <stdint.h>

#define NB 4
#define NN 2048
#define NA 128
#define NK 2048                         /* table intervals; knots 0..NK */
#define RMINF 5.8f
#define RMAXF 6.0f
#define PI_OVER_DR 15.707963267948966f  /* pi / (RMAX-RMIN) */

typedef __attribute__((ext_vector_type(8))) short short8v;   // 8 bf16 (MFMA A/B frag)
typedef __attribute__((ext_vector_type(4))) float f32x4;     // MFMA C/D frag

// Exact tanh via exp: tanh(x) = 1 - 2/(e^{2x}+1). ~7 VALU inst, rel err ~1e-6.
__device__ __forceinline__ float fast_tanh(float x)
{
    x = fminf(fmaxf(x, -15.f), 15.f);
    float e = __expf(2.f * x);
    float r = __builtin_amdgcn_rcpf(e + 1.f);
    return fmaf(-2.f, r, 1.f);
}

__device__ __forceinline__ uint16_t bf16_of(float x)
{
    __hip_bfloat16 b = __float2bfloat16(x);
    return *(uint16_t*)&b;
}

__device__ __forceinline__ float bf16_to_f(uint16_t v)
{
    union { uint32_t u; float f; } c; c.u = ((uint32_t)v) << 16; return c.f;
}

// Fragment-major packed element offset for an MFMA-A/B-side matrix X[R][Ktot]:
// tile (16 r x 32 k) = 512 contiguous elems; within tile, lane-major per the
// 16x16x32 frag map (lane = (r&15) + kg*16, elems k = kg*8..kg*8+7).
__device__ __forceinline__ size_t packed_off(int r, int k, int Ktot)
{
    return ((size_t)((r >> 4) * (Ktot >> 5) + (k >> 5)) << 9)
         + (((r & 15) + (((k >> 3) & 3) << 4)) << 3) + (k & 7);
}

// S value for table knot (shared by both table kernels).
__device__ __forceinline__ float knot_S(int knot)
{
    float uu = (float)knot / (float)NK;
    return (knot == NK) ? 1e8f : uu / (1.f - uu);
}

// ---------------------------------------------------------------------------
// Table stage A: H2[knot][j] = tanh(be1[j] + sum_k tanh(S*We0[k]+be0[k])*We1[k][j])
// ---------------------------------------------------------------------------
__global__ void prep_h2_kernel(
    const float* __restrict__ We0, const float* __restrict__ be0,
    const float* __restrict__ We1, const float* __restrict__ be1,
    float* __restrict__ H2)
{
    int idx = blockIdx.x * 256 + threadIdx.x;
    if (idx >= (NK + 1) * 50) return;
    int knot = idx / 50, j = idx - knot * 50;
    float S = knot_S(knot);
    float acc = be1[j];
    #pragma unroll
    for (int k = 0; k < 25; ++k) {
        float h1k = fast_tanh(fmaf(S, We0[k], be0[k]));
        acc = fmaf(h1k, We1[k * 50 + j], acc);
    }
    H2[idx] = fast_tanh(acc);
}

// ---------------------------------------------------------------------------
// Table stage B: TBL[knot][j] = tanh(be2[j] + sum_k H2[knot][k]*We2[k][j]).
// ---------------------------------------------------------------------------
__global__ void prep_tbl_kernel(
    const float* __restrict__ H2,
    const float* __restrict__ We2, const float* __restrict__ be2,
    float* __restrict__ TBL)
{
    int idx = blockIdx.x * 256 + threadIdx.x;
    if (idx >= (NK + 1) * 100) return;
    int knot = idx / 100, j = idx - knot * 100;
    const float* h2 = H2 + knot * 50;
    float acc = be2[j];
    #pragma unroll
    for (int k = 0; k < 50; ++k)
        acc = fmaf(h2[k], We2[k * 100 + j], acc);
    TBL[idx] = fast_tanh(acc);
}

// ---------------------------------------------------------------------------
// Prep: fitting weight W [K][240] fp32 -> Wt hi/lo PACKED [256][KP] bf16.
// ---------------------------------------------------------------------------
__global__ void prep_wt_kernel(const float* __restrict__ W,
                               uint16_t* __restrict__ Whi,
                               uint16_t* __restrict__ Wlo,
                               int K, int KP)
{
    int idx = blockIdx.x * 256 + threadIdx.x;
    if (idx < 256 * KP) {
        int colN = idx / KP, k = idx - colN * KP;
        float v = (colN < 240 && k < K) ? W[k * 240 + colN] : 0.f;
        uint16_t hi = bf16_of(v);
        size_t off = packed_off(colN, k, KP);
        Whi[off] = hi;
        Wlo[off] = bf16_of(v - bf16_to_f(hi));
    }
}

// ---------------------------------------------------------------------------
// Descriptor kernel v20: j-quad gather, math-before-prefetch ordering (t0/t1
// consumed then overwritten -> no shadow copies), in-loop broadcast Ri read.
// Goal: natural VGPR <= 64 -> 8 waves/SIMD. DR single bf16 plane PACKED.
// ---------------------------------------------------------------------------
__global__ __launch_bounds__(256) void desc_kernel(
    const float* __restrict__ dR, const int* __restrict__ neigh,
    const float* __restrict__ TBL,
    uint16_t* __restrict__ DRhi)
{
    const int bid = blockIdx.x;
    const int atom = (bid & 7) * 1024 + (bid >> 3);   // bijection on [0,8192)
    const int t = threadIdx.x;

    __shared__ float4 RiSh[128];
    __shared__ float2 IFSh[128];            // (frac, as_float(ia*100))
    __shared__ float  tmpPart[8][4][100];   // 12.8 KB
    __shared__ float  tmpBf[4][100];
    __shared__ unsigned long long balls[2];

    // ---- phase A: one thread per neighbor (t<128) ----
    float x = 0.f, y = 0.f, z = 0.f, S = 0.f, s_inv = 1.f;
    if (t < 128) {
        const int base = atom * NA;
        x = dR[(base + t) * 3 + 0];
        y = dR[(base + t) * 3 + 1];
        z = dR[(base + t) * 3 + 2];
        int nb = neigh[base + t];
        float Rij = x * x + y * y + z * z;      // squared distance (ref quirk)
        bool mask = nb > 0;
        bool mask_min = Rij < RMINF;
        float safe = (Rij > 0.f) ? Rij : 1.f;
        s_inv = 1.f / safe;
        float s_cos = 0.5f * cosf((Rij - RMINF) * PI_OVER_DR) + 0.5f;
        S = (mask && mask_min) ? s_inv
          : ((!mask_min && Rij < RMAXF) ? s_cos : 0.f);
        unsigned long long bal = __ballot(mask);
        if ((t & 63) == 0) balls[t >> 6] = bal;
    }
    __syncthreads();   // #1: balls visible

    if (t < 128) {
        unsigned long long nb0 = ~balls[0], nb1 = ~balls[1];
        int firstBad;
        if (nb0)       firstBad = __ffsll((long long)nb0) - 1;
        else if (nb1)  firstBad = 64 + __ffsll((long long)nb1) - 1;
        else           firstBad = 128;
        float f = (t < firstBad) ? (S * s_inv) : 0.f;
        RiSh[t] = make_float4(S, f * x, f * y, f * z);
        float uu = S / (1.f + S);               // match prep map exactly
        float pos = fminf(uu * (float)NK, (float)NK - 0.001f);
        float fi = floorf(pos);
        IFSh[t] = make_float2(pos - fi, __int_as_float((int)fi * 100));
    }
    __syncthreads();   // #2: RiSh + IFSh ready

    // ---- phase B: j-quad gather-contraction ----
    const int aq = t >> 5;          // 0..7 -> a-chunk of 16
    const int jq = t & 31;          // j-quad index, active < 25
    if (jq < 25) {
        const float* TBLq = TBL + jq * 4;
        const int a0 = aq * 16;
        float acc00 = 0.f, acc01 = 0.f, acc02 = 0.f, acc03 = 0.f;
        float acc10 = 0.f, acc11 = 0.f, acc12 = 0.f, acc13 = 0.f;
        float acc20 = 0.f, acc21 = 0.f, acc22 = 0.f, acc23 = 0.f;
        float acc30 = 0.f, acc31 = 0.f, acc32 = 0.f, acc33 = 0.f;

        float2 ifv = IFSh[a0];
        float  cf  = ifv.x;
        int    ia  = __float_as_int(ifv.y);
        float4 t0  = *(const float4*)(TBLq + ia);
        float4 t1  = *(const float4*)(TBLq + ia + 100);
        #pragma unroll
        for (int i = 0; i < 16; ++i) {
            // lerp consumes t0/t1 -> they die here
            float g0 = fmaf(cf, t1.x - t0.x, t0.x);
            float g1 = fmaf(cf, t1.y - t0.y, t0.y);
            float g2 = fmaf(cf, t1.z - t0.z, t0.z);
            float g3 = fmaf(cf, t1.w - t0.w, t0.w);
            if (i + 1 < 16) {                   // overwrite dead t0/t1
                float2 nx = IFSh[a0 + i + 1];
                cf = nx.x;
                int ian = __float_as_int(nx.y);
                t0 = *(const float4*)(TBLq + ian);
                t1 = *(const float4*)(TBLq + ian + 100);
            }
            float4 cri = RiSh[a0 + i];          // broadcast LDS read
            acc00 = fmaf(cri.x, g0, acc00); acc01 = fmaf(cri.x, g1, acc01);
            acc02 = fmaf(cri.x, g2, acc02); acc03 = fmaf(cri.x, g3, acc03);
            acc10 = fmaf(cri.y, g0, acc10); acc11 = fmaf(cri.y, g1, acc11);
            acc12 = fmaf(cri.y, g2, acc12); acc13 = fmaf(cri.y, g3, acc13);
            acc20 = fmaf(cri.z, g0, acc20); acc21 = fmaf(cri.z, g1, acc21);
            acc22 = fmaf(cri.z, g2, acc22); acc23 = fmaf(cri.z, g3, acc23);
            acc30 = fmaf(cri.w, g0, acc30); acc31 = fmaf(cri.w, g1, acc31);
            acc32 = fmaf(cri.w, g2, acc32); acc33 = fmaf(cri.w, g3, acc33);
        }
        *(float4*)&tmpPart[aq][0][jq * 4] = make_float4(acc00, acc01, acc02, acc03);
        *(float4*)&tmpPart[aq][1][jq * 4] = make_float4(acc10, acc11, acc12, acc13);
        *(float4*)&tmpPart[aq][2][jq * 4] = make_float4(acc20, acc21, acc22, acc23);
        *(float4*)&tmpPart[aq][3][jq * 4] = make_float4(acc30, acc31, acc32, acc33);
    }
    __syncthreads();   // #3

    // ---- reduce 8 a-chunks ----
    for (int idx = t; idx < 400; idx += 256) {
        int c = idx / 100, j = idx - c * 100;
        float s = tmpPart[0][c][j] + tmpPart[1][c][j]
                + tmpPart[2][c][j] + tmpPart[3][c][j]
                + tmpPart[4][c][j] + tmpPart[5][c][j]
                + tmpPart[6][c][j] + tmpPart[7][c][j];
        tmpBf[c][j] = s;
    }
    __syncthreads();   // #4

    // ---- phase C: DR[i][M] -> single bf16 plane PACKED; i split by half ----
    const int half = t >> 7;
    const int u = t & 127;
    if (u < 100) {
        float b0 = tmpBf[0][u];
        float b1 = tmpBf[1][u];
        float b2 = tmpBf[2][u];
        float b3 = tmpBf[3][u];
        const int i0 = half * 8;
        #pragma unroll
        for (int ii = 0; ii < 8; ++ii) {
            int i = i0 + ii;
            float v = tmpBf[0][i] * b0 + tmpBf[1][i] * b1
                    + tmpBf[2][i] * b2 + tmpBf[3][i] * b3;
            DRhi[packed_off(atom, i * 100 + u, 1600)] = bf16_of(v);
        }
    }
}

// ---------------------------------------------------------------------------
// GEMM partials from PACKED operands: Part[z][8192][256] (fp32, row-major).
// 2-term (A single plane): used for gemm1 (K=1600, KSPLIT=2).
// ---------------------------------------------------------------------------
template<int KP, int KSPLIT>
__global__ __launch_bounds__(256, 4) void gemm_part(
    const uint16_t* __restrict__ Ahi,
    const uint16_t* __restrict__ Wthi, const uint16_t* __restrict__ Wtlo,
    float* __restrict__ Part)
{
    constexpr int KT = KP >> 5;
    constexpr int STEPS = KT / KSPLIT;
    const int tid = threadIdx.x;
    const int wid = tid >> 6, lane = tid & 63;
    const int mg = wid >> 1, ng = wid & 1;
    const int mt0 = blockIdx.x * 4 + mg * 2;
    const int nt0 = blockIdx.y * 4 + ng * 2;
    const int kt0 = blockIdx.z * STEPS;

    const size_t aB0 = ((size_t)(mt0 + 0) * KT + kt0) * 512 + lane * 8;
    const size_t aB1 = ((size_t)(mt0 + 1) * KT + kt0) * 512 + lane * 8;
    const size_t bB0 = ((size_t)(nt0 + 0) * KT + kt0) * 512 + lane * 8;
    const size_t bB1 = ((size_t)(nt0 + 1) * KT + kt0) * 512 + lane * 8;

    f32x4 acc[2][2];
    #pragma unroll
    for (int m = 0; m < 2; ++m)
        #pragma unroll
        for (int n = 0; n < 2; ++n) acc[m][n] = (f32x4){0.f, 0.f, 0.f, 0.f};

    short8v f[2][6];

#define LOADSET(B, S) do {                                       \
        f[B][0] = *(const short8v*)(Ahi  + aB0 + (S) * 512);     \
        f[B][1] = *(const short8v*)(Ahi  + aB1 + (S) * 512);     \
        f[B][2] = *(const short8v*)(Wthi + bB0 + (S) * 512);     \
        f[B][3] = *(const short8v*)(Wthi + bB1 + (S) * 512);     \
        f[B][4] = *(const short8v*)(Wtlo + bB0 + (S) * 512);     \
        f[B][5] = *(const short8v*)(Wtlo + bB1 + (S) * 512);     \
    } while (0)

    LOADSET(0, 0);
    #pragma unroll
    for (int s = 0; s < STEPS; ++s) {
        const int b = s & 1;
        if (s + 1 < STEPS) LOADSET(b ^ 1, s + 1);
        #pragma unroll
        for (int m = 0; m < 2; ++m)
            #pragma unroll
            for (int n = 0; n < 2; ++n) {
                acc[m][n] = __builtin_amdgcn_mfma_f32_16x16x32_bf16(f[b][m], f[b][2 + n], acc[m][n], 0, 0, 0);
                acc[m][n] = __builtin_amdgcn_mfma_f32_16x16x32_bf16(f[b][m], f[b][4 + n], acc[m][n], 0, 0, 0);
            }
    }
#undef LOADSET

    const int ar = lane & 15, kg = lane >> 4;
    float* pp = Part + (size_t)blockIdx.z * (8192 * 256);
    #pragma unroll
    for (int m = 0; m < 2; ++m)
        #pragma unroll
        for (int n = 0; n < 2; ++n)
            #pragma unroll
            for (int r = 0; r < 4; ++r)
                pp[(size_t)((mt0 + m) * 16 + kg * 4 + r) * 256 + (nt0 + n) * 16 + ar] = acc[m][n][r];
}

// ---------------------------------------------------------------------------
// Fused small GEMM (K=256, A split hi/lo, 3-term) with bias+tanh epilogue,
// writing bf16 hi/lo PACKED directly. Each block covers 64x64 = 8 whole
// 1KB packed tiles -> no cross-block partial lines, no swizzle needed.
// ---------------------------------------------------------------------------
template<int KP>
__global__ __launch_bounds__(256, 4) void gemm_fused(
    const uint16_t* __restrict__ Ahi, const uint16_t* __restrict__ Alo,
    const uint16_t* __restrict__ Wthi, const uint16_t* __restrict__ Wtlo,
    const float* __restrict__ bias,
    uint16_t* __restrict__ Ohi, uint16_t* __restrict__ Olo)
{
    constexpr int KT = KP >> 5;
    constexpr int STEPS = KT;
    const int tid = threadIdx.x;
    const int wid = tid >> 6, lane = tid & 63;
    const int mg = wid >> 1, ng = wid & 1;
    const int mt0 = blockIdx.x * 4 + mg * 2;
    const int nt0 = blockIdx.y * 4 + ng * 2;

    const size_t aB0 = ((size_t)(mt0 + 0) * KT) * 512 + lane * 8;
    const size_t aB1 = ((size_t)(mt0 + 1) * KT) * 512 + lane * 8;
    const size_t bB0 = ((size_t)(nt0 + 0) * KT) * 512 + lane * 8;
    const size_t bB1 = ((size_t)(nt0 + 1) * KT) * 512 + lane * 8;

    f32x4 acc[2][2];
    #pragma unroll
    for (int m = 0; m < 2; ++m)
        #pragma unroll
        for (int n = 0; n < 2; ++n) acc[m][n] = (f32x4){0.f, 0.f, 0.f, 0.f};

    short8v f[2][8];

#define LOADSET(B, S) do {                                       \
        f[B][0] = *(const short8v*)(Ahi  + aB0 + (S) * 512);     \
        f[B][1] = *(const short8v*)(Ahi  + aB1 + (S) * 512);     \
        f[B][2] = *(const short8v*)(Alo  + aB0 + (S) * 512);     \
        f[B][3] = *(const short8v*)(Alo  + aB1 + (S) * 512);     \
        f[B][4] = *(const short8v*)(Wthi + bB0 + (S) * 512);     \
        f[B][5] = *(const short8v*)(Wthi + bB1 + (S) * 512);     \
        f[B][6] = *(const short8v*)(Wtlo + bB0 + (S) * 512);     \
        f[B][7] = *(const short8v*)(Wtlo + bB1 + (S) * 512);     \
    } while (0)

    LOADSET(0, 0);
    #pragma unroll
    for (int s = 0; s < STEPS; ++s) {
        const int b = s & 1;
        if (s + 1 < STEPS) LOADSET(b ^ 1, s + 1);
        #pragma unroll
        for (int m = 0; m < 2; ++m)
            #pragma unroll
            for (int n = 0; n < 2; ++n) {
                acc[m][n] = __builtin_amdgcn_mfma_f32_16x16x32_bf16(f[b][m],     f[b][4 + n], acc[m][n], 0, 0, 0);
                acc[m][n] = __builtin_amdgcn_mfma_f32_16x16x32_bf16(f[b][m],     f[b][6 + n], acc[m][n], 0, 0, 0);
                acc[m][n] = __builtin_amdgcn_mfma_f32_16x16x32_bf16(f[b][2 + m], f[b][4 + n], acc[m][n], 0, 0, 0);
            }
    }
#undef LOADSET

    const int ar = lane & 15, kg = lane >> 4;
    #pragma unroll
    for (int n = 0; n < 2; ++n) {
        int col = (nt0 + n) * 16 + ar;
        bool valid = col < 240;
        float bv = valid ? bias[col] : 0.f;
        #pragma unroll
        for (int m = 0; m < 2; ++m) {
            #pragma unroll
            for (int r = 0; r < 4; ++r) {
                int row = (mt0 + m) * 16 + kg * 4 + r;
                float v = valid ? fast_tanh(acc[m][n][r] + bv) : 0.f;
                uint16_t hi = bf16_of(v);
                size_t off = packed_off(row, col, 256);
                Ohi[off] = hi;
                Olo[off] = bf16_of(v - bf16_to_f(hi));
            }
        }
    }
}

// ---------------------------------------------------------------------------
// Epilogue for gemm1: O = tanh(sum_z Part[z] + bias) -> bf16 hi/lo PACKED.
// XCD-swizzled so the 4 blocks covering each 16-row packed tile share an L2.
// ---------------------------------------------------------------------------
__global__ __launch_bounds__(256) void gemm_epi(
    const float* __restrict__ Part, const float* __restrict__ bias,
    uint16_t* __restrict__ Ohi, uint16_t* __restrict__ Olo)
{
    int g = (blockIdx.x & 7) * 256 + (blockIdx.x >> 3);   // bijection on [0,2048)
    int idx0 = g * 1024 + threadIdx.x;
    #pragma unroll
    for (int it = 0; it < 4; ++it) {
        int idx = idx0 + it * 256;
        int col = idx & 255;
        int row = idx >> 8;
        float s = Part[idx] + Part[idx + 8192 * 256];
        float v = (col < 240) ? fast_tanh(s + bias[col]) : 0.f;
        uint16_t hi = bf16_of(v);
        size_t off = packed_off(row, col, 256);
        Ohi[off] = hi;
        Olo[off] = bf16_of(v - bf16_to_f(hi));
    }
}

// ---------------------------------------------------------------------------
// Ei = (h_hi+h_lo) @ Wf3 + bf3 : one wave per atom; H is PACKED (Ktot=256).
// ---------------------------------------------------------------------------
__global__ __launch_bounds__(256) void final_dot_kernel(
    const uint16_t* __restrict__ Hhi, const uint16_t* __restrict__ Hlo,
    const float* __restrict__ Wf3, const float* __restrict__ bf3,
    float* __restrict__ out)
{
    int wave = threadIdx.x >> 6, lane = threadIdx.x & 63;
    int atom = blockIdx.x * 4 + wave;
    float v = 0.f;
    if (lane < 60) {
        size_t off = packed_off(atom, lane * 4, 256);
        ushort4 h4 = *(const ushort4*)(Hhi + off);
        ushort4 l4 = *(const ushort4*)(Hlo + off);
        float4 w = *(const float4*)&Wf3[lane * 4];
        v = (bf16_to_f(h4.x) + bf16_to_f(l4.x)) * w.x
          + (bf16_to_f(h4.y) + bf16_to_f(l4.y)) * w.y
          + (bf16_to_f(h4.z) + bf16_to_f(l4.z)) * w.z
          + (bf16_to_f(h4.w) + bf16_to_f(l4.w)) * w.w;
    }
    #pragma unroll
    for (int off = 32; off; off >>= 1) v += __shfl_down(v, off, 64);
    if (lane == 0) out[4 + atom] = v + bf3[0];
}

__global__ __launch_bounds__(256) void etot_kernel(float* __restrict__ out)
{
    __shared__ float red[256];
    int b = blockIdx.x, t = threadIdx.x;
    float s = 0.f;
    for (int i = t; i < NN; i += 256) s += out[4 + b * NN + i];
    red[t] = s;
    __syncthreads();
    for (int w = 128; w; w >>= 1) {
        if (t < w) red[t] += red[t + w];
        __syncthreads();
    }
    if (t == 0) out[b] = red[0];
}

// ---------------------------------------------------------------------------
extern "C" void kernel_launch(void* const* d_in, const int* in_sizes, int n_in,
                              void* d_out, int out_size, void* d_ws, size_t ws_size,
                              hipStream_t stream)
{
    const float* dR    = (const float*)d_in[0];
    const int*   neigh = (const int*)d_in[1];
    const float* We0   = (const float*)d_in[2];
    const float* be0   = (const float*)d_in[3];
    const float* We1   = (const float*)d_in[4];
    const float* be1   = (const float*)d_in[5];
    const float* We2   = (const float*)d_in[6];
    const float* be2   = (const float*)d_in[7];
    const float* Wf0   = (const float*)d_in[8];
    const float* bf0   = (const float*)d_in[9];
    const float* Wf1   = (const float*)d_in[10];
    const float* bf1   = (const float*)d_in[11];
    const float* Wf2   = (const float*)d_in[12];
    const float* bf2   = (const float*)d_in[13];
    const float* Wf3   = (const float*)d_in[14];
    const float* bf3   = (const float*)d_in[15];
    float* out = (float*)d_out;

    char* ws = (char*)d_ws;
    uint16_t* Wt0hi  = (uint16_t*)(ws + 32768);               // 819200
    uint16_t* Wt0lo  = (uint16_t*)(ws + 851968);              // 819200
    uint16_t* Wt1hi  = (uint16_t*)(ws + 1671168);             // 131072
    uint16_t* Wt1lo  = (uint16_t*)(ws + 1802240);             // 131072
    uint16_t* Wt2hi  = (uint16_t*)(ws + 1933312);             // 131072
    uint16_t* Wt2lo  = (uint16_t*)(ws + 2064384);             // 131072
    uint16_t* DRhi   = (uint16_t*)(ws + 2195456);             // 26214400
    uint16_t* hAhi   = (uint16_t*)(ws + 54624256);            // 4194304
    uint16_t* hAlo   = (uint16_t*)(ws + 58818560);            // 4194304
    uint16_t* hBhi   = (uint16_t*)(ws + 63012864);            // 4194304
    uint16_t* hBlo   = (uint16_t*)(ws + 67207168);            // 4194304
    // H2 (410KB) aliases hAhi: written by prep_h2, read by prep_tbl,
    // dead before epi1 writes hA.
    float* H2  = (float*)(ws + 54624256);
    // TBL (820KB) aliases hBhi: read by desc before gemm1 overwrites w/ Part1.
    float* TBL = (float*)(ws + 63012864);
    // Part1 (2x8.4MB fp32) aliases [hBhi..]: written by gemm1 (TBL dead),
    // read by epi1 (writes hA, disjoint), dead before gemm_fused writes hB.
    float* Part1 = (float*)(ws + 63012864);

    prep_h2_kernel<<<401, 256, 0, stream>>>(We0, be0, We1, be1, H2);
    prep_tbl_kernel<<<801, 256, 0, stream>>>(H2, We2, be2, TBL);
    prep_wt_kernel<<<1600, 256, 0, stream>>>(Wf0, Wt0hi, Wt0lo, 1600, 1600);
    prep_wt_kernel<<<256, 256, 0, stream>>>(Wf1, Wt1hi, Wt1lo, 240, 256);
    prep_wt_kernel<<<256, 256, 0, stream>>>(Wf2, Wt2hi, Wt2lo, 240, 256);

    desc_kernel<<<NB * NN, 256, 0, stream>>>(dR, neigh, TBL, DRhi);

    gemm_part<1600, 2><<<dim3(128, 4, 2), 256, 0, stream>>>(DRhi, Wt0hi, Wt0lo, Part1);
    gemm_epi<<<2048, 256, 0, stream>>>(Part1, bf0, hAhi, hAlo);
    gemm_fused<256><<<dim3(128, 4), 256, 0, stream>>>(hAhi, hAlo, Wt1hi, Wt1lo, bf1, hBhi, hBlo);
    gemm_fused<256><<<dim3(128, 4), 256, 0, stream>>>(hBhi, hBlo, Wt2hi, Wt2lo, bf2, hAhi, hAlo);

    final_dot_kernel<<<NB * NN / 4, 256, 0, stream>>>(hAhi, hAlo, Wf3, bf3, out);
    etot_kernel<<<NB, 256, 0, stream>>>(out);
}